// Round 13
// baseline (170.021 us; speedup 1.0000x reference)
//
#include <hip/hip_runtime.h>
#include <hip/hip_bf16.h>

typedef short short8 __attribute__((ext_vector_type(8)));
typedef float f32x4 __attribute__((ext_vector_type(4)));

#define HD 64
#define N_EN 8
#define N_AL 7
#define E_FEAT 9
#define A_FEAT 10
#define OWN_FEAT 16
#define N_ACT 14
#define EW2 641
#define AW2 640

#define PW 640
#define HALF 20480
#define AG_OFF 0
#define AG_STR 264
#define GATES_OFF 4352
#define GT_STR 520
#define AU_OFF 12672
#define AU_STR 136
#define U_OFF 14848

#define BE_OFF 0
#define BA_OFF 40960
#define BG_OFF 81920
#define BU_OFF 114688
#define WS_US 119808

__device__ __forceinline__ ushort f2u(float x) {
    __hip_bfloat16 b = __float2bfloat16(x);
    ushort u; __builtin_memcpy(&u, &b, 2); return u;
}
__device__ __forceinline__ float u2f(uint u) {
    union { uint x; float f; } c; c.x = u << 16; return c.f;
}
__device__ __forceinline__ uint pk2(float a, float b) {
    return (uint)f2u(a) | ((uint)f2u(b) << 16);
}
__device__ __forceinline__ float sigm(float x) { return 1.f / (1.f + __expf(-x)); }

__device__ __forceinline__ short8 lda_swz(const ushort* P_us, int row, int s, int g) {
    const int mm = (row & 7) << 3;
    const int o = s * 32 + g * 4;
    const ushort* pr = P_us + row * PW;
    union { short8 v; uint2 q[2]; } u;
    u.q[0] = *(const uint2*)(pr + (o ^ mm));
    u.q[1] = *(const uint2*)(pr + ((o + 16) ^ mm));
    return u.v;
}
__device__ __forceinline__ short8 lda_lin(const char* base, int row, int strideB, int s, int g) {
    const char* p = base + row * strideB + s * 64 + g * 8;
    union { short8 v; uint2 q[2]; } u;
    u.q[0] = *(const uint2*)p;
    u.q[1] = *(const uint2*)(p + 32);
    return u.v;
}

// ---------------- prep ----------------
__global__ __launch_bounds__(256) void prep_kernel(
    const float* __restrict__ he_w2, const float* __restrict__ he_b2,
    const float* __restrict__ ha_w2, const float* __restrict__ ha_b2,
    const float* __restrict__ fc1_own_w, const float* __restrict__ fc1_own_b,
    const float* __restrict__ agent_id_emb, const float* __restrict__ action_id_emb,
    const float* __restrict__ gru_w_ih, const float* __restrict__ gru_w_hh,
    const float* __restrict__ gru_b_ih, const float* __restrict__ gru_b_hh,
    const float* __restrict__ fc2_w, const float* __restrict__ fc2_b,
    ushort* __restrict__ ws, float* __restrict__ fbias)
{
    const int GE = 80, GA = 80, GG = 64, GU = 10;
    const int TT = (GE + GA + GG + GU) * 64;   // 14976
    int idx = blockIdx.x * 256 + threadIdx.x;
    if (idx < TT) {
        int grp = idx >> 6, lane = idx & 63;
        int g = lane >> 4, col16 = lane & 15;
        int table, s, t, slot;
        if (grp < GE)                { table = 0; int q = grp;                s = q / 4;  t = q % 4;  slot = q * 64 + lane; }
        else if (grp < GE + GA)      { table = 1; int q = grp - GE;           s = q / 4;  t = q % 4;  slot = q * 64 + lane; }
        else if (grp < GE + GA + GG) { table = 2; int q = grp - GE - GA;      s = q / 16; t = q % 16; slot = q * 64 + lane; }
        else                         { table = 3; int q = grp - GE - GA - GG; s = q / 5;  t = q % 5;  slot = q * 64 + lane; }
        const int j = t * 16 + col16;
        ushort out[8];
        #pragma unroll
        for (int e = 0; e < 8; ++e) {
            int kk = 32 * s + 4 * g + (e & 3) + 16 * (e >> 2);
            float v = 0.f;
            if (table == 0) {
                if (kk < 576)       v = he_w2[(kk & 63) * EW2 + (kk >> 6) * HD + j];
                else if (kk < 585)  v = he_b2[(kk - 576) * HD + j];
                else if (kk < 601)  v = fc1_own_w[(kk - 585) * HD + j];
                else if (kk == 601) v = fc1_own_b[j];
                else if (kk < 610)  v = agent_id_emb[(kk - 602) * HD + j];
                else if (kk < 624)  v = action_id_emb[(kk - 610) * HD + j];
                else if (kk < 634)  v = ha_b2[(kk - 624) * HD + j];
            } else if (table == 1) {
                v = ha_w2[(kk & 63) * AW2 + (kk >> 6) * HD + j];
            } else if (table == 2) {
                int gb2 = j >> 6, c = j & 63;
                int jj = (gb2 == 0) ? c : (gb2 == 1) ? 64 + c : 128 + c;
                if (gb2 <= 1)      v = (kk < 64) ? gru_w_ih[jj * HD + kk] : gru_w_hh[jj * HD + kk - 64];
                else if (gb2 == 2) v = (kk < 64) ? gru_w_ih[jj * HD + kk] : 0.f;
                else               v = (kk >= 64) ? gru_w_hh[jj * HD + kk - 64] : 0.f;
            } else {
                if (j < 64)       v = he_w2[j * EW2 + 576 + kk];
                else if (j < 70)  v = fc2_w[kk * 6 + (j - 64)];
                else if (j == 70) v = he_b2[576 + kk];
            }
            out[e] = f2u(v);
        }
        ushort* dst = ws + ((table == 0) ? BE_OFF : (table == 1) ? BA_OFF : (table == 2) ? BG_OFF : BU_OFF);
        *(short8*)(dst + (size_t)slot * 8) = *(short8*)out;
    } else {
        int b = idx - TT;
        if (b < 128)       fbias[b] = gru_b_ih[b] + gru_b_hh[b];
        else if (b < 192)  fbias[b] = gru_b_ih[b];
        else if (b < 256)  fbias[b] = gru_b_hh[b - 64];
        else if (b < 320)  fbias[b] = he_w2[(size_t)(b - 256) * EW2 + 640];
        else if (b < 326)  fbias[b] = fc2_b[b - 320];
        else if (b == 326) fbias[256 + 70] = he_b2[640];
    }
}

// ---------------- entity-math helpers ----------------
__device__ __forceinline__ void ent_e(const float* w1, float b1, const float* ef, float* pf) {
    float acc = b1;
    #pragma unroll
    for (int f = 0; f < E_FEAT; ++f) acc += ef[f] * w1[f];
    const float r = fmaxf(acc, 0.f);
    #pragma unroll
    for (int f = 0; f < E_FEAT; ++f) pf[f] += r * ef[f];
}
__device__ __forceinline__ void ent_a(const float* w1, float b1, const float* af, float* pf) {
    float acc = b1;
    #pragma unroll
    for (int f = 0; f < A_FEAT; ++f) acc += af[f] * w1[f];
    const float r = fmaxf(acc, 0.f);
    #pragma unroll
    for (int f = 0; f < A_FEAT; ++f) pf[f] += r * af[f];
}

// ---------------- stage helpers ----------------
__device__ __forceinline__ void pbuild_ally_row(
    ushort* P_us, const float* __restrict__ ally_feats,
    const float* w1, float b1, int n, int row, int lane)
{
    const int mm = (row & 7) << 3;
    ushort* Pr = P_us + row * PW;
    const float2* R2 = (const float2*)(ally_feats + (size_t)n * (N_AL * A_FEAT));
    float pf[A_FEAT];
    #pragma unroll
    for (int f = 0; f < A_FEAT; ++f) pf[f] = 0.f;
    #pragma unroll
    for (int p = 0; p < 3; ++p) {
        float wb[20];
        #pragma unroll
        for (int i = 0; i < 10; ++i) { float2 v = R2[10 * p + i]; wb[2 * i] = v.x; wb[2 * i + 1] = v.y; }
        ent_a(w1, b1, wb, pf);
        ent_a(w1, b1, wb + 10, pf);
    }
    {
        float wb[10];
        #pragma unroll
        for (int i = 0; i < 5; ++i) { float2 v = R2[30 + i]; wb[2 * i] = v.x; wb[2 * i + 1] = v.y; }
        ent_a(w1, b1, wb, pf);
    }
    #pragma unroll
    for (int f = 0; f < A_FEAT; ++f) Pr[(f * HD + lane) ^ mm] = f2u(pf[f]);
}

__device__ __forceinline__ void pbuild_enemy_row(
    ushort* P_us,
    const float* __restrict__ enemy_feats, const float* __restrict__ ally_feats,
    const float* __restrict__ own_feats,
    const int* __restrict__ agent_idx, const int* __restrict__ last_act_idx,
    const float* w1, float b1, int n, int row, int lane)
{
    const int mm = (row & 7) << 3;
    ushort* Pr = P_us + row * PW;
    const float* efb = enemy_feats + (size_t)n * (N_EN * E_FEAT);
    const float4* R4 = (const float4*)efb;
    float pf[E_FEAT];
    #pragma unroll
    for (int f = 0; f < E_FEAT; ++f) pf[f] = 0.f;
    #pragma unroll
    for (int p = 0; p < 4; ++p) {
        const int base = (p == 0) ? 0 : (p == 1) ? 4 : (p == 2) ? 9 : 13;
        const int off  = (p & 1) ? 2 : 0;
        float wb[20];
        #pragma unroll
        for (int i = 0; i < 5; ++i) {
            float4 v = R4[base + i];
            wb[4 * i] = v.x; wb[4 * i + 1] = v.y; wb[4 * i + 2] = v.z; wb[4 * i + 3] = v.w;
        }
        ent_e(w1, b1, wb + off, pf);
        ent_e(w1, b1, wb + off + 9, pf);
    }
    #pragma unroll
    for (int f = 0; f < E_FEAT; ++f) Pr[(f * HD + lane) ^ mm] = f2u(pf[f]);
    if (lane < E_FEAT) {
        float sv = 0.f;
        #pragma unroll
        for (int e = 0; e < N_EN; ++e) sv += efb[e * E_FEAT + lane];
        Pr[(576 + lane) ^ mm] = f2u(sv);
    }
    if (lane < OWN_FEAT) Pr[(585 + lane) ^ mm] = f2u(own_feats[(size_t)n * OWN_FEAT + lane]);
    if (lane == 0) Pr[601 ^ mm] = 0x3F80;
    const int ai = agent_idx[n], la = last_act_idx[n];
    if (lane < 8)     Pr[(602 + lane) ^ mm] = (lane == ai) ? (ushort)0x3F80 : (ushort)0;
    if (lane < N_ACT) Pr[(610 + lane) ^ mm] = (lane == la) ? (ushort)0x3F80 : (ushort)0;
    if (lane < A_FEAT) {
        const float* afb = ally_feats + (size_t)n * (N_AL * A_FEAT);
        float sv = 0.f;
        #pragma unroll
        for (int e = 0; e < N_AL; ++e) sv += afb[e * A_FEAT + lane];
        Pr[(624 + lane) ^ mm] = f2u(sv);
    }
}

// dual-group GEMM: one b-load feeds both groups' MFMAs
__device__ __forceinline__ void gemm20_dual(f32x4& accA, f32x4& accB,
    const ushort* PA, const ushort* PB, const ushort* bt,
    int wv, int lane, int arow, int g)
{
    #pragma unroll
    for (int s = 0; s < 20; ++s) {
        short8 b = *(const short8*)(bt + ((size_t)(s * 4 + wv) * 64 + lane) * 8);
        short8 aA = lda_swz(PA, arow, s, g);
        short8 aB = lda_swz(PB, arow, s, g);
        accA = __builtin_amdgcn_mfma_f32_16x16x32_bf16(aA, b, accA, 0, 0, 0);
        accB = __builtin_amdgcn_mfma_f32_16x16x32_bf16(aB, b, accB, 0, 0, 0);
    }
}

__device__ __forceinline__ void stageAG(char* H, const f32x4& acc,
    const float* __restrict__ hidden_state, int n0g, int tid, int wv, int arow, int g)
{
    char* AGb = H + AG_OFF;
    #pragma unroll
    for (int j = 0; j < 4; ++j)
        *(ushort*)(AGb + (g * 4 + j) * AG_STR + (wv * 16 + arow) * 2) = f2u(fmaxf(acc[j], 0.f));
    const int row = tid >> 4, c4 = (tid & 15) * 4;
    float4 h4 = *(const float4*)(hidden_state + (size_t)(n0g + row) * HD + c4);
    char* p = AGb + row * AG_STR + (64 + c4) * 2;
    *(uint*)p       = pk2(h4.x, h4.y);
    *(uint*)(p + 4) = pk2(h4.z, h4.w);
}

// dual-group GRU GEMM: shared b across groups
__device__ __forceinline__ void gru_gemm_dual(char* HA, char* HB, const ushort* __restrict__ ws,
                                              int wv, int lane, int arow, int g)
{
    f32x4 accGA[4] = {{0.f,0.f,0.f,0.f},{0.f,0.f,0.f,0.f},{0.f,0.f,0.f,0.f},{0.f,0.f,0.f,0.f}};
    f32x4 accGB[4] = {{0.f,0.f,0.f,0.f},{0.f,0.f,0.f,0.f},{0.f,0.f,0.f,0.f},{0.f,0.f,0.f,0.f}};
    #pragma unroll
    for (int s = 0; s < 4; ++s) {
        short8 aA = lda_lin(HA + AG_OFF, arow, AG_STR, s, g);
        short8 aB = lda_lin(HB + AG_OFF, arow, AG_STR, s, g);
        #pragma unroll
        for (int tt = 0; tt < 4; ++tt) {
            const int t = wv * 4 + tt;
            short8 b = *(const short8*)(ws + BG_OFF + ((size_t)(s * 16 + t) * 64 + lane) * 8);
            accGA[tt] = __builtin_amdgcn_mfma_f32_16x16x32_bf16(aA, b, accGA[tt], 0, 0, 0);
            accGB[tt] = __builtin_amdgcn_mfma_f32_16x16x32_bf16(aB, b, accGB[tt], 0, 0, 0);
        }
    }
    #pragma unroll
    for (int tt = 0; tt < 4; ++tt)
        #pragma unroll
        for (int j = 0; j < 4; ++j) {
            const int jc = ((wv * 4 + tt) * 16 + arow) * 2;
            *(ushort*)(HA + GATES_OFF + (g * 4 + j) * GT_STR + jc) = f2u(accGA[tt][j]);
            *(ushort*)(HB + GATES_OFF + (g * 4 + j) * GT_STR + jc) = f2u(accGB[tt][j]);
        }
}

__device__ __forceinline__ void pointwise(char* H, const float* __restrict__ hidden_state,
    const float* __restrict__ fbias, float* __restrict__ out_hh, int n0g, int tid)
{
    const int row = tid >> 4, c4 = (tid & 15) * 4;
    const char* gb = H + GATES_OFF + row * GT_STR;
    uint2 rv = *(const uint2*)(gb + c4 * 2);
    uint2 zv = *(const uint2*)(gb + 128 + c4 * 2);
    uint2 iv = *(const uint2*)(gb + 256 + c4 * 2);
    uint2 nv = *(const uint2*)(gb + 384 + c4 * 2);
    float4 bR = *(const float4*)(fbias + c4);
    float4 bZ = *(const float4*)(fbias + 64 + c4);
    float4 bI = *(const float4*)(fbias + 128 + c4);
    float4 bH = *(const float4*)(fbias + 192 + c4);
    float4 h4 = *(const float4*)(hidden_state + (size_t)(n0g + row) * HD + c4);
    float gr[4] = {u2f(rv.x & 0xffffu) + bR.x, u2f(rv.x >> 16) + bR.y, u2f(rv.y & 0xffffu) + bR.z, u2f(rv.y >> 16) + bR.w};
    float gz[4] = {u2f(zv.x & 0xffffu) + bZ.x, u2f(zv.x >> 16) + bZ.y, u2f(zv.y & 0xffffu) + bZ.z, u2f(zv.y >> 16) + bZ.w};
    float gi[4] = {u2f(iv.x & 0xffffu) + bI.x, u2f(iv.x >> 16) + bI.y, u2f(iv.y & 0xffffu) + bI.z, u2f(iv.y >> 16) + bI.w};
    float gn[4] = {u2f(nv.x & 0xffffu) + bH.x, u2f(nv.x >> 16) + bH.y, u2f(nv.y & 0xffffu) + bH.z, u2f(nv.y >> 16) + bH.w};
    float hcur[4] = {h4.x, h4.y, h4.z, h4.w};
    float hh[4];
    #pragma unroll
    for (int cc = 0; cc < 4; ++cc) {
        const float r = sigm(gr[cc]);
        const float z = sigm(gz[cc]);
        const float nng = tanhf(gi[cc] + r * gn[cc]);
        hh[cc] = (1.f - z) * nng + z * hcur[cc];
    }
    *(float4*)(out_hh + (size_t)(n0g + row) * HD + c4) = make_float4(hh[0], hh[1], hh[2], hh[3]);
    char* p = H + AU_OFF + row * AU_STR + c4 * 2;
    *(uint*)p       = pk2(hh[0], hh[1]);
    *(uint*)(p + 4) = pk2(hh[2], hh[3]);
}

// dual-group u-GEMM: shared b
__device__ __forceinline__ void u_gemm_dual(char* HA, char* HB, const ushort* __restrict__ ws,
    const float* __restrict__ fbias, float* __restrict__ out_q,
    int n0A, int n0B, int wv, int lane, int arow, int g)
{
    f32x4 accUA = {0.f,0.f,0.f,0.f}, accUB = {0.f,0.f,0.f,0.f};
    f32x4 accQA = {0.f,0.f,0.f,0.f}, accQB = {0.f,0.f,0.f,0.f};
    #pragma unroll
    for (int s = 0; s < 2; ++s) {
        short8 aA = lda_lin(HA + AU_OFF, arow, AU_STR, s, g);
        short8 aB = lda_lin(HB + AU_OFF, arow, AU_STR, s, g);
        short8 b = *(const short8*)(ws + BU_OFF + ((size_t)(s * 5 + wv) * 64 + lane) * 8);
        accUA = __builtin_amdgcn_mfma_f32_16x16x32_bf16(aA, b, accUA, 0, 0, 0);
        accUB = __builtin_amdgcn_mfma_f32_16x16x32_bf16(aB, b, accUB, 0, 0, 0);
        if (wv == 0) {
            short8 b2 = *(const short8*)(ws + BU_OFF + ((size_t)(s * 5 + 4) * 64 + lane) * 8);
            accQA = __builtin_amdgcn_mfma_f32_16x16x32_bf16(aA, b2, accQA, 0, 0, 0);
            accQB = __builtin_amdgcn_mfma_f32_16x16x32_bf16(aB, b2, accQB, 0, 0, 0);
        }
    }
    float* uldA = (float*)(HA + U_OFF);
    float* uldB = (float*)(HB + U_OFF);
    #pragma unroll
    for (int j = 0; j < 4; ++j) {
        uldA[(g * 4 + j) * 66 + wv * 16 + arow] = accUA[j];
        uldB[(g * 4 + j) * 66 + wv * 16 + arow] = accUB[j];
    }
    if (wv == 0) {
        #pragma unroll
        for (int j = 0; j < 4; ++j) {
            const int m = g * 4 + j;
            if (arow < 6) {
                out_q[(size_t)(n0A + m) * N_ACT + arow] = accQA[j] + fbias[320 + arow];
                out_q[(size_t)(n0B + m) * N_ACT + arow] = accQB[j] + fbias[320 + arow];
            } else if (arow == 6) {
                uldA[m * 66 + 64] = accQA[j];
                uldB[m * 66 + 64] = accQB[j];
            }
        }
    }
}

__device__ __forceinline__ void attack(char* H, const float* __restrict__ enemy_feats,
    const float* __restrict__ he_w1, const float* __restrict__ he_b1,
    const float* __restrict__ fbias, float* __restrict__ out_q,
    int n0g, int wv, int lane)
{
    float w1[E_FEAT];
    #pragma unroll
    for (int f = 0; f < E_FEAT; ++f) w1[f] = he_w1[f * HD + lane];
    const float b1 = he_b1[lane];
    const float ubl = fbias[256 + lane];
    const float cb = fbias[256 + 70];
    const float* uld = (const float*)(H + U_OFF);
    #pragma unroll
    for (int rr = 0; rr < 4; ++rr) {
        const int row = wv * 4 + rr, n = n0g + row;
        const float uk = uld[row * 66 + lane] + ubl;
        const float ct = uld[row * 66 + 64] + cb;
        const float4* R4 = (const float4*)(enemy_feats + (size_t)n * (N_EN * E_FEAT));
        float p[N_EN];
        #pragma unroll
        for (int pp = 0; pp < 4; ++pp) {
            const int base = (pp == 0) ? 0 : (pp == 1) ? 4 : (pp == 2) ? 9 : 13;
            const int off  = (pp & 1) ? 2 : 0;
            float wb[20];
            #pragma unroll
            for (int i = 0; i < 5; ++i) {
                float4 v = R4[base + i];
                wb[4 * i] = v.x; wb[4 * i + 1] = v.y; wb[4 * i + 2] = v.z; wb[4 * i + 3] = v.w;
            }
            float a0 = b1, a1 = b1;
            #pragma unroll
            for (int f = 0; f < E_FEAT; ++f) { a0 += wb[off + f] * w1[f]; a1 += wb[off + 9 + f] * w1[f]; }
            p[2 * pp]     = fmaxf(a0, 0.f) * uk;
            p[2 * pp + 1] = fmaxf(a1, 0.f) * uk;
        }
        #pragma unroll
        for (int o = 1; o < 64; o <<= 1) {
            #pragma unroll
            for (int e = 0; e < N_EN; ++e) p[e] += __shfl_xor(p[e], o);
        }
        if (lane < N_EN) {
            float pv = p[0];
            #pragma unroll
            for (int e = 1; e < N_EN; ++e) if (lane == e) pv = p[e];
            out_q[(size_t)n * N_ACT + 6 + lane] = pv + ct;
        }
    }
}

// ---------------- main: dual-group with SHARED b-loads ----------------
__global__ __launch_bounds__(256, 2) void agent_kernel(
    const float* __restrict__ own_feats,
    const float* __restrict__ enemy_feats,
    const float* __restrict__ ally_feats,
    const float* __restrict__ hidden_state,
    const int*  __restrict__ agent_idx,
    const int*  __restrict__ last_act_idx,
    const float* __restrict__ he_w1, const float* __restrict__ he_b1,
    const float* __restrict__ ha_w1, const float* __restrict__ ha_b1,
    const ushort* __restrict__ ws, const float* __restrict__ fbias,
    float* __restrict__ out_q, float* __restrict__ out_hh)
{
    __shared__ __align__(16) char smem[2 * HALF];
    const int tid = threadIdx.x, lane = tid & 63, wv = tid >> 6;
    const int arow = lane & 15, g = lane >> 4;
    const int n0A = blockIdx.x * 32, n0B = n0A + 16;
    ushort* PA = (ushort*)smem;
    ushort* PB = (ushort*)(smem + HALF);
    char* HA = smem;
    char* HB = smem + HALF;

    f32x4 accA = {0.f, 0.f, 0.f, 0.f}, accB = {0.f, 0.f, 0.f, 0.f};

    // S1: pbuild ally A + B
    {
        float w1[A_FEAT];
        #pragma unroll
        for (int f = 0; f < A_FEAT; ++f) w1[f] = ha_w1[f * HD + lane];
        const float b1 = ha_b1[lane];
        #pragma unroll
        for (int rr = 0; rr < 4; ++rr) {
            pbuild_ally_row(PA, ally_feats, w1, b1, n0A + wv * 4 + rr, wv * 4 + rr, lane);
            pbuild_ally_row(PB, ally_feats, w1, b1, n0B + wv * 4 + rr, wv * 4 + rr, lane);
        }
    }
    __syncthreads();
    // S2: ally GEMM both groups, shared b
    gemm20_dual(accA, accB, PA, PB, ws + BA_OFF, wv, lane, arow, g);
    __syncthreads();
    // S3: pbuild enemy A + B
    {
        float w1[E_FEAT];
        #pragma unroll
        for (int f = 0; f < E_FEAT; ++f) w1[f] = he_w1[f * HD + lane];
        const float b1 = he_b1[lane];
        #pragma unroll
        for (int rr = 0; rr < 4; ++rr) {
            pbuild_enemy_row(PA, enemy_feats, ally_feats, own_feats, agent_idx, last_act_idx,
                             w1, b1, n0A + wv * 4 + rr, wv * 4 + rr, lane);
            pbuild_enemy_row(PB, enemy_feats, ally_feats, own_feats, agent_idx, last_act_idx,
                             w1, b1, n0B + wv * 4 + rr, wv * 4 + rr, lane);
        }
    }
    __syncthreads();
    // S4: enemy GEMM both groups, shared b
    gemm20_dual(accA, accB, PA, PB, ws + BE_OFF, wv, lane, arow, g);
    __syncthreads();
    // S5: stage A_gru both groups
    stageAG(HA, accA, hidden_state, n0A, tid, wv, arow, g);
    stageAG(HB, accB, hidden_state, n0B, tid, wv, arow, g);
    __syncthreads();
    // S6: GRU GEMM both groups, shared b
    gru_gemm_dual(HA, HB, ws, wv, lane, arow, g);
    __syncthreads();
    // S7: pointwise both groups
    pointwise(HA, hidden_state, fbias, out_hh, n0A, tid);
    pointwise(HB, hidden_state, fbias, out_hh, n0B, tid);
    __syncthreads();
    // S8: u-GEMM both groups, shared b
    u_gemm_dual(HA, HB, ws, fbias, out_q, n0A, n0B, wv, lane, arow, g);
    __syncthreads();
    // S9: attack both groups
    attack(HA, enemy_feats, he_w1, he_b1, fbias, out_q, n0A, wv, lane);
    attack(HB, enemy_feats, he_w1, he_b1, fbias, out_q, n0B, wv, lane);
}

extern "C" void kernel_launch(void* const* d_in, const int* in_sizes, int n_in,
                              void* d_out, int out_size, void* d_ws, size_t ws_size,
                              hipStream_t stream) {
    const float* own_feats    = (const float*)d_in[0];
    const float* enemy_feats  = (const float*)d_in[1];
    const float* ally_feats   = (const float*)d_in[2];
    const float* hidden_state = (const float*)d_in[3];
    const int*  agent_idx     = (const int*)d_in[4];
    const int*  last_act      = (const int*)d_in[5];
    const float* fc1_own_w = (const float*)d_in[7];
    const float* fc1_own_b = (const float*)d_in[8];
    const float* agent_id_emb  = (const float*)d_in[9];
    const float* action_id_emb = (const float*)d_in[10];
    const float* he_w1 = (const float*)d_in[11];
    const float* he_b1 = (const float*)d_in[12];
    const float* he_w2 = (const float*)d_in[13];
    const float* he_b2 = (const float*)d_in[14];
    const float* ha_w1 = (const float*)d_in[15];
    const float* ha_b1 = (const float*)d_in[16];
    const float* ha_w2 = (const float*)d_in[17];
    const float* ha_b2 = (const float*)d_in[18];
    const float* gru_w_ih = (const float*)d_in[19];
    const float* gru_w_hh = (const float*)d_in[20];
    const float* gru_b_ih = (const float*)d_in[21];
    const float* gru_b_hh = (const float*)d_in[22];
    const float* fc2_w = (const float*)d_in[23];
    const float* fc2_b = (const float*)d_in[24];

    const int R = in_sizes[0] / OWN_FEAT;  // 32768
    ushort* ws = (ushort*)d_ws;
    float* fbias = (float*)(ws + WS_US);
    float* out_q  = (float*)d_out;
    float* out_hh = out_q + (size_t)R * N_ACT;

    prep_kernel<<<60, 256, 0, stream>>>(
        he_w2, he_b2, ha_w2, ha_b2, fc1_own_w, fc1_own_b,
        agent_id_emb, action_id_emb, gru_w_ih, gru_w_hh, gru_b_ih, gru_b_hh,
        fc2_w, fc2_b, ws, fbias);

    agent_kernel<<<R / 32, 256, 0, stream>>>(
        own_feats, enemy_feats, ally_feats, hidden_state, agent_idx, last_act,
        he_w1, he_b1, ha_w1, ha_b1, ws, fbias, out_q, out_hh);
}

// Round 14
// 100.822 us; speedup vs baseline: 1.6863x; 1.6863x over previous
//
#include <hip/hip_runtime.h>
#include <hip/hip_bf16.h>

typedef short short8 __attribute__((ext_vector_type(8)));
typedef float f32x4 __attribute__((ext_vector_type(4)));

#define HD 64
#define N_EN 8
#define N_AL 7
#define E_FEAT 9
#define A_FEAT 10
#define OWN_FEAT 16
#define N_ACT 14
#define EW2 641
#define AW2 640

// GEMM K sizes (padded to multiples of 32)
#define KSE 20   // enemy: K=640
#define KSA 21   // ally : K=672
#define KSG 5    // gru  : K=160
#define KSU 3    // u    : K=96

// B-fragment tables in ws (ushort units)
#define BE_OFF 0
#define BE_CNT (KSE*4*64*8)
#define BA_OFF (BE_OFF+BE_CNT)
#define BA_CNT (KSA*4*64*8)
#define BG_OFF (BA_OFF+BA_CNT)
#define BG_CNT (KSG*16*64*8)
#define BU_OFF (BG_OFF+BG_CNT)
#define BU_CNT (KSU*5*64*8)
#define WS_SHORTS (BU_OFF+BU_CNT)   // 132608 shorts = 265216 B

// LDS layout (bytes). Regions reuse the P area across phases.
#define P_STRIDE 676          // ushorts/row (>= KA, mult of 4)
#define LDS_AG 0              // A_gru [16] rows, stride 328 B
#define LDS_GATES 8192        // gates [16] rows, stride 520 B
#define LDS_AU 17024          // A_u [16] rows, stride 200 B
#define LDS_U 0               // u_lds [16][66] f32
#define LDS_BYTES 21632

__device__ __forceinline__ ushort f2u(float x) {
    __hip_bfloat16 b = __float2bfloat16(x);
    ushort u; __builtin_memcpy(&u, &b, 2); return u;
}
__device__ __forceinline__ float u2f(uint u) {
    union { uint x; float f; } c; c.x = u << 16; return c.f;
}
__device__ __forceinline__ uint pk2(float a, float b) {
    return (uint)f2u(a) | ((uint)f2u(b) << 16);
}
__device__ __forceinline__ float sigm(float x) { return 1.f / (1.f + __expf(-x)); }
// A-fragment: two ds_read_b64; elems 0-3 = kk, 4-7 = kk+16
__device__ __forceinline__ short8 lda(const char* base, int row, int strideB, int s, int g) {
    const char* p = base + row * strideB + s * 64 + g * 8;
    union { short8 v; uint2 q[2]; } u;
    u.q[0] = *(const uint2*)p;
    u.q[1] = *(const uint2*)(p + 32);
    return u.v;
}

// ---------------- prep: build B-fragment tables ----------------
__global__ __launch_bounds__(256) void prep_kernel(
    const float* __restrict__ he_w2, const float* __restrict__ he_b2,
    const float* __restrict__ ha_w2, const float* __restrict__ ha_b2,
    const float* __restrict__ fc1_own_w, const float* __restrict__ fc1_own_b,
    const float* __restrict__ agent_id_emb, const float* __restrict__ action_id_emb,
    const float* __restrict__ gru_w_ih, const float* __restrict__ gru_w_hh,
    const float* __restrict__ gru_b_ih, const float* __restrict__ gru_b_hh,
    const float* __restrict__ fc2_w, const float* __restrict__ fc2_b,
    ushort* __restrict__ ws)
{
    const int GE = KSE * 4, GA = KSA * 4, GG = KSG * 16, GU = KSU * 5;
    const int total = (GE + GA + GG + GU) * 64;
    int idx = blockIdx.x * 256 + threadIdx.x;
    if (idx >= total) return;
    int grp = idx >> 6, lane = idx & 63;
    int g = lane >> 4, col16 = lane & 15;
    int table, s, t, slot;
    if (grp < GE)           { table = 0; int q = grp;            s = q / 4;  t = q % 4;  slot = q * 64 + lane; }
    else if (grp < GE + GA) { table = 1; int q = grp - GE;       s = q / 4;  t = q % 4;  slot = q * 64 + lane; }
    else if (grp < GE + GA + GG) { table = 2; int q = grp - GE - GA; s = q / 16; t = q % 16; slot = q * 64 + lane; }
    else                    { table = 3; int q = grp - GE - GA - GG; s = q / 5; t = q % 5; slot = q * 64 + lane; }
    const int j = t * 16 + col16;
    ushort out[8];
    #pragma unroll
    for (int e = 0; e < 8; ++e) {
        int kk = 32 * s + 4 * g + (e & 3) + 16 * (e >> 2);
        float v = 0.f;
        if (table == 0) {
            if (kk < 576)      { int f = kk >> 6, k = kk & 63; v = he_w2[k * EW2 + f * HD + j]; }
            else if (kk < 585) { int f = kk - 576; v = he_b2[f * HD + j]; }
            else if (kk < 601) { int f = kk - 585; v = fc1_own_w[f * HD + j]; }
            else if (kk == 601){ v = fc1_own_b[j]; }
            else if (kk < 610) { int a = kk - 602; v = agent_id_emb[a * HD + j]; }
            else if (kk < 624) { int a = kk - 610; v = action_id_emb[a * HD + j]; }
        } else if (table == 1) {
            if (kk < 640)      { int f = kk >> 6, k = kk & 63; v = ha_w2[k * AW2 + f * HD + j]; }
            else if (kk < 650) { int f = kk - 640; v = ha_b2[f * HD + j]; }
        } else if (table == 2) {
            int gb = j >> 6, c = j & 63;
            if (gb <= 1) {
                int jj = gb * 64 + c;
                if (kk < 64)        v = gru_w_ih[jj * HD + kk];
                else if (kk < 128)  v = gru_w_hh[jj * HD + kk - 64];
                else if (kk == 128) v = gru_b_ih[jj] + gru_b_hh[jj];
            } else if (gb == 2) {
                int jj = 128 + c;
                if (kk < 64)        v = gru_w_ih[jj * HD + kk];
                else if (kk == 128) v = gru_b_ih[jj];
            } else {
                int jj = 128 + c;
                if (kk >= 64 && kk < 128) v = gru_w_hh[jj * HD + kk - 64];
                else if (kk == 128)       v = gru_b_hh[jj];
            }
        } else {
            if (j < 64) {
                if (kk < 64)       v = he_w2[j * EW2 + 576 + kk];
                else if (kk == 64) v = he_w2[j * EW2 + 640];
            } else if (j < 70) {
                int o = j - 64;
                if (kk < 64)       v = fc2_w[kk * 6 + o];
                else if (kk == 64) v = fc2_b[o];
            } else if (j == 70) {
                if (kk < 64)       v = he_b2[576 + kk];
                else if (kk == 64) v = he_b2[640];
            }
        }
        out[e] = f2u(v);
    }
    ushort* dst = ws + ((table == 0) ? BE_OFF : (table == 1) ? BA_OFF : (table == 2) ? BG_OFF : BU_OFF);
    *(short8*)(dst + slot * 8) = *(short8*)out;
}

// ---------------- main: fused, 4 waves / 16 rows; VGPR capped for 6 waves/SIMD ----------------
__global__ __launch_bounds__(256, 3) void agent_kernel(
    const float* __restrict__ own_feats,
    const float* __restrict__ enemy_feats,
    const float* __restrict__ ally_feats,
    const float* __restrict__ hidden_state,
    const int*  __restrict__ agent_idx,
    const int*  __restrict__ last_act_idx,
    const float* __restrict__ he_w1, const float* __restrict__ he_b1,
    const float* __restrict__ ha_w1, const float* __restrict__ ha_b1,
    const ushort* __restrict__ ws,
    float* __restrict__ out_q, float* __restrict__ out_hh)
{
    __shared__ __align__(16) char smem[LDS_BYTES];
    const int tid  = threadIdx.x;
    const int lane = tid & 63;
    const int wv   = tid >> 6;
    const int n0   = blockIdx.x * 16;
    const int arow = lane & 15;
    const int g    = lane >> 4;
    ushort* P = (ushort*)smem;

    // ===== Phase 1: enemy P-build (wave-private rows 4wv..4wv+3) =====
    {
        float w1[E_FEAT];
        #pragma unroll
        for (int f = 0; f < E_FEAT; ++f) w1[f] = he_w1[f * HD + lane];
        const float b1 = he_b1[lane];
        #pragma unroll
        for (int rr = 0; rr < 4; ++rr) {
            const int row = wv * 4 + rr, n = n0 + row;
            const float* efb = enemy_feats + (size_t)n * (N_EN * E_FEAT);
            float pf[E_FEAT], sf[E_FEAT];
            #pragma unroll
            for (int f = 0; f < E_FEAT; ++f) { pf[f] = 0.f; sf[f] = 0.f; }
            #pragma unroll
            for (int e = 0; e < N_EN; ++e) {
                float ef[E_FEAT];
                #pragma unroll
                for (int f = 0; f < E_FEAT; ++f) ef[f] = efb[e * E_FEAT + f];
                float acc = b1;
                #pragma unroll
                for (int f = 0; f < E_FEAT; ++f) acc += ef[f] * w1[f];
                const float r = fmaxf(acc, 0.f);
                #pragma unroll
                for (int f = 0; f < E_FEAT; ++f) { pf[f] += r * ef[f]; sf[f] += ef[f]; }
            }
            ushort* Pr = P + row * P_STRIDE;
            #pragma unroll
            for (int f = 0; f < E_FEAT; ++f) Pr[f * HD + lane] = f2u(pf[f]);
            if (lane == 0) {
                #pragma unroll
                for (int f = 0; f < E_FEAT; ++f) Pr[576 + f] = f2u(sf[f]);
                Pr[601] = 0x3F80;
            }
            if (lane < OWN_FEAT) Pr[585 + lane] = f2u(own_feats[(size_t)n * OWN_FEAT + lane]);
            const int ai = agent_idx[n], la = last_act_idx[n];
            if (lane < 8)      Pr[602 + lane] = (lane == ai) ? 0x3F80 : 0;
            if (lane < N_ACT)  Pr[610 + lane] = (lane == la) ? 0x3F80 : 0;
            if (lane < 16)     Pr[624 + lane] = 0;
        }
    }
    __syncthreads();

    // ===== Phase 2: enemy GEMM (bounded unroll to limit in-flight b-loads) =====
    f32x4 accE = {0.f, 0.f, 0.f, 0.f};
    #pragma unroll 5
    for (int s = 0; s < KSE; ++s) {
        short8 b = *(const short8*)(ws + BE_OFF + ((size_t)(s * 4 + wv) * 64 + lane) * 8);
        short8 a = lda(smem, arow, P_STRIDE * 2, s, g);
        accE = __builtin_amdgcn_mfma_f32_16x16x32_bf16(a, b, accE, 0, 0, 0);
    }
    __syncthreads();

    // ===== Phase 3: ally P-build =====
    {
        float w1[A_FEAT];
        #pragma unroll
        for (int f = 0; f < A_FEAT; ++f) w1[f] = ha_w1[f * HD + lane];
        const float b1 = ha_b1[lane];
        #pragma unroll
        for (int rr = 0; rr < 4; ++rr) {
            const int row = wv * 4 + rr, n = n0 + row;
            const float* afb = ally_feats + (size_t)n * (N_AL * A_FEAT);
            float pf[A_FEAT], sf[A_FEAT];
            #pragma unroll
            for (int f = 0; f < A_FEAT; ++f) { pf[f] = 0.f; sf[f] = 0.f; }
            #pragma unroll
            for (int e = 0; e < N_AL; ++e) {
                float af[A_FEAT];
                #pragma unroll
                for (int f = 0; f < A_FEAT; ++f) af[f] = afb[e * A_FEAT + f];
                float acc = b1;
                #pragma unroll
                for (int f = 0; f < A_FEAT; ++f) acc += af[f] * w1[f];
                const float r = fmaxf(acc, 0.f);
                #pragma unroll
                for (int f = 0; f < A_FEAT; ++f) { pf[f] += r * af[f]; sf[f] += af[f]; }
            }
            ushort* Pr = P + row * P_STRIDE;
            #pragma unroll
            for (int f = 0; f < A_FEAT; ++f) Pr[f * HD + lane] = f2u(pf[f]);
            if (lane == 0) {
                #pragma unroll
                for (int f = 0; f < A_FEAT; ++f) Pr[640 + f] = f2u(sf[f]);
            }
            if (lane < 22) Pr[650 + lane] = 0;
        }
    }
    __syncthreads();

    // ===== Phase 4: ally GEMM (bounded unroll) =====
    #pragma unroll 7
    for (int s = 0; s < KSA; ++s) {
        short8 b = *(const short8*)(ws + BA_OFF + ((size_t)(s * 4 + wv) * 64 + lane) * 8);
        short8 a = lda(smem, arow, P_STRIDE * 2, s, g);
        accE = __builtin_amdgcn_mfma_f32_16x16x32_bf16(a, b, accE, 0, 0, 0);
    }
    __syncthreads();

    // ===== Phase 5: stage A_gru = [x | h | 1 | 0] =====
    float4 h4s;   // kept for phase 7 (same thread mapping)
    #pragma unroll
    for (int j = 0; j < 4; ++j) {
        const int m = g * 4 + j;
        *(ushort*)(smem + LDS_AG + m * 328 + (wv * 16 + arow) * 2) = f2u(fmaxf(accE[j], 0.f));
    }
    {
        const int row = tid >> 4, c4 = (tid & 15) * 4;
        h4s = *(const float4*)(hidden_state + (size_t)(n0 + row) * HD + c4);
        char* p = smem + LDS_AG + row * 328 + (64 + c4) * 2;
        *(uint*)p       = pk2(h4s.x, h4s.y);
        *(uint*)(p + 4) = pk2(h4s.z, h4s.w);
        if (tid < 16) *(ushort*)(smem + LDS_AG + tid * 328 + 128 * 2) = 0x3F80;
        for (int i = tid; i < 16 * 31; i += 256) {
            int r2 = i / 31, c = 129 + i % 31;
            *(ushort*)(smem + LDS_AG + r2 * 328 + c * 2) = 0;
        }
    }
    __syncthreads();

    // ===== Phase 6: GRU GEMM (N=256) =====
    {
        f32x4 accG[4] = {{0.f,0.f,0.f,0.f},{0.f,0.f,0.f,0.f},{0.f,0.f,0.f,0.f},{0.f,0.f,0.f,0.f}};
        #pragma unroll
        for (int s = 0; s < KSG; ++s) {
            short8 a = lda(smem + LDS_AG, arow, 328, s, g);
            #pragma unroll
            for (int tt = 0; tt < 4; ++tt) {
                const int t = wv * 4 + tt;
                short8 b = *(const short8*)(ws + BG_OFF + ((size_t)(s * 16 + t) * 64 + lane) * 8);
                accG[tt] = __builtin_amdgcn_mfma_f32_16x16x32_bf16(a, b, accG[tt], 0, 0, 0);
            }
        }
        #pragma unroll
        for (int tt = 0; tt < 4; ++tt)
            #pragma unroll
            for (int j = 0; j < 4; ++j) {
                const int m = g * 4 + j, jc = (wv * 4 + tt) * 16 + arow;
                *(ushort*)(smem + LDS_GATES + m * 520 + jc * 2) = f2u(accG[tt][j]);
            }
    }
    __syncthreads();

    // ===== Phase 7: pointwise GRU + stage A_u (h reused from phase 5) =====
    {
        const int row = tid >> 4, c4 = (tid & 15) * 4;
        const char* gb = smem + LDS_GATES + row * 520;
        uint2 rv = *(const uint2*)(gb + c4 * 2);
        uint2 zv = *(const uint2*)(gb + 128 + c4 * 2);
        uint2 iv = *(const uint2*)(gb + 256 + c4 * 2);
        uint2 nv = *(const uint2*)(gb + 384 + c4 * 2);
        float hr[4] = {u2f(rv.x & 0xffffu), u2f(rv.x >> 16), u2f(rv.y & 0xffffu), u2f(rv.y >> 16)};
        float hz[4] = {u2f(zv.x & 0xffffu), u2f(zv.x >> 16), u2f(zv.y & 0xffffu), u2f(zv.y >> 16)};
        float hi[4] = {u2f(iv.x & 0xffffu), u2f(iv.x >> 16), u2f(iv.y & 0xffffu), u2f(iv.y >> 16)};
        float hn[4] = {u2f(nv.x & 0xffffu), u2f(nv.x >> 16), u2f(nv.y & 0xffffu), u2f(nv.y >> 16)};
        float hcur[4] = {h4s.x, h4s.y, h4s.z, h4s.w};
        float hh[4];
        #pragma unroll
        for (int cc = 0; cc < 4; ++cc) {
            const float r = sigm(hr[cc]);
            const float z = sigm(hz[cc]);
            const float nng = tanhf(hi[cc] + r * hn[cc]);
            hh[cc] = (1.f - z) * nng + z * hcur[cc];
        }
        *(float4*)(out_hh + (size_t)(n0 + row) * HD + c4) = make_float4(hh[0], hh[1], hh[2], hh[3]);
        char* p = smem + LDS_AU + row * 200 + c4 * 2;
        *(uint*)p       = pk2(hh[0], hh[1]);
        *(uint*)(p + 4) = pk2(hh[2], hh[3]);
        if (tid < 16) *(ushort*)(smem + LDS_AU + tid * 200 + 64 * 2) = 0x3F80;
        for (int i = tid; i < 16 * 31; i += 256) {
            int r2 = i / 31, c = 65 + i % 31;
            *(ushort*)(smem + LDS_AU + r2 * 200 + c * 2) = 0;
        }
    }
    __syncthreads();

    // ===== Phase 8: u-GEMM (N=80) =====
    {
        f32x4 accU = {0.f, 0.f, 0.f, 0.f};
        f32x4 accQ = {0.f, 0.f, 0.f, 0.f};
        #pragma unroll
        for (int s = 0; s < KSU; ++s) {
            short8 a = lda(smem + LDS_AU, arow, 200, s, g);
            short8 b = *(const short8*)(ws + BU_OFF + ((size_t)(s * 5 + wv) * 64 + lane) * 8);
            accU = __builtin_amdgcn_mfma_f32_16x16x32_bf16(a, b, accU, 0, 0, 0);
            if (wv == 0) {
                short8 b2 = *(const short8*)(ws + BU_OFF + ((size_t)(s * 5 + 4) * 64 + lane) * 8);
                accQ = __builtin_amdgcn_mfma_f32_16x16x32_bf16(a, b2, accQ, 0, 0, 0);
            }
        }
        float* uld = (float*)(smem + LDS_U);
        #pragma unroll
        for (int j = 0; j < 4; ++j) {
            const int m = g * 4 + j;
            uld[m * 66 + wv * 16 + arow] = accU[j];
        }
        if (wv == 0) {
            #pragma unroll
            for (int j = 0; j < 4; ++j) {
                const int m = g * 4 + j;
                if (arow < 6)       out_q[(size_t)(n0 + m) * N_ACT + arow] = accQ[j];
                else if (arow == 6) uld[m * 66 + 64] = accQ[j];
            }
        }
    }
    __syncthreads();

    // ===== Phase 9: attack head (r recomputed; wave wv owns rows 4wv..4wv+3) =====
    {
        float w1[E_FEAT];
        #pragma unroll
        for (int f = 0; f < E_FEAT; ++f) w1[f] = he_w1[f * HD + lane];
        const float b1 = he_b1[lane];
        const float* uld = (const float*)(smem + LDS_U);
        #pragma unroll
        for (int rr = 0; rr < 4; ++rr) {
            const int row = wv * 4 + rr, n = n0 + row;
            const float uk = uld[row * 66 + lane];
            const float ct = uld[row * 66 + 64];
            const float* efb = enemy_feats + (size_t)n * (N_EN * E_FEAT);
            float p[N_EN];
            #pragma unroll
            for (int e = 0; e < N_EN; ++e) {
                float acc = b1;
                #pragma unroll
                for (int f = 0; f < E_FEAT; ++f) acc += efb[e * E_FEAT + f] * w1[f];
                p[e] = fmaxf(acc, 0.f) * uk;
            }
            #pragma unroll
            for (int o = 1; o < 64; o <<= 1) {
                #pragma unroll
                for (int e = 0; e < N_EN; ++e) p[e] += __shfl_xor(p[e], o);
            }
            if (lane < N_EN) {
                float pv = p[0];
                #pragma unroll
                for (int e = 1; e < N_EN; ++e) if (lane == e) pv = p[e];
                out_q[(size_t)n * N_ACT + 6 + lane] = pv + ct;
            }
        }
    }
}

extern "C" void kernel_launch(void* const* d_in, const int* in_sizes, int n_in,
                              void* d_out, int out_size, void* d_ws, size_t ws_size,
                              hipStream_t stream) {
    const float* own_feats    = (const float*)d_in[0];
    const float* enemy_feats  = (const float*)d_in[1];
    const float* ally_feats   = (const float*)d_in[2];
    const float* hidden_state = (const float*)d_in[3];
    const int*  agent_idx     = (const int*)d_in[4];
    const int*  last_act      = (const int*)d_in[5];
    const float* fc1_own_w = (const float*)d_in[7];
    const float* fc1_own_b = (const float*)d_in[8];
    const float* agent_id_emb  = (const float*)d_in[9];
    const float* action_id_emb = (const float*)d_in[10];
    const float* he_w1 = (const float*)d_in[11];
    const float* he_b1 = (const float*)d_in[12];
    const float* he_w2 = (const float*)d_in[13];
    const float* he_b2 = (const float*)d_in[14];
    const float* ha_w1 = (const float*)d_in[15];
    const float* ha_b1 = (const float*)d_in[16];
    const float* ha_w2 = (const float*)d_in[17];
    const float* ha_b2 = (const float*)d_in[18];
    const float* gru_w_ih = (const float*)d_in[19];
    const float* gru_w_hh = (const float*)d_in[20];
    const float* gru_b_ih = (const float*)d_in[21];
    const float* gru_b_hh = (const float*)d_in[22];
    const float* fc2_w = (const float*)d_in[23];
    const float* fc2_b = (const float*)d_in[24];

    const int R = in_sizes[0] / OWN_FEAT;  // 32768
    ushort* ws = (ushort*)d_ws;
    float* out_q  = (float*)d_out;
    float* out_hh = out_q + (size_t)R * N_ACT;

    prep_kernel<<<65, 256, 0, stream>>>(
        he_w2, he_b2, ha_w2, ha_b2, fc1_own_w, fc1_own_b,
        agent_id_emb, action_id_emb, gru_w_ih, gru_w_hh, gru_b_ih, gru_b_hh,
        fc2_w, fc2_b, ws);

    agent_kernel<<<R / 16, 256, 0, stream>>>(
        own_feats, enemy_feats, ally_feats, hidden_state, agent_idx, last_act,
        he_w1, he_b1, ha_w1, ha_b1, ws, out_q, out_hh);
}

// Round 15
// 97.225 us; speedup vs baseline: 1.7487x; 1.0370x over previous
//
#include <hip/hip_runtime.h>
#include <hip/hip_bf16.h>

typedef short short8 __attribute__((ext_vector_type(8)));
typedef float f32x4 __attribute__((ext_vector_type(4)));

#define HD 64
#define N_EN 8
#define N_AL 7
#define E_FEAT 9
#define A_FEAT 10
#define OWN_FEAT 16
#define N_ACT 14
#define EW2 641
#define AW2 640

// GEMM K sizes (padded to multiples of 32)
#define KSE 20   // enemy: K=640
#define KSA 21   // ally : K=672
#define KSG 5    // gru  : K=160
#define KSU 3    // u    : K=96

// B-fragment tables in ws (ushort units)
#define BE_OFF 0
#define BE_CNT (KSE*4*64*8)
#define BA_OFF (BE_OFF+BE_CNT)
#define BA_CNT (KSA*4*64*8)
#define BG_OFF (BA_OFF+BA_CNT)
#define BG_CNT (KSG*16*64*8)
#define BU_OFF (BG_OFF+BG_CNT)
#define BU_CNT (KSU*5*64*8)
#define WS_SHORTS (BU_OFF+BU_CNT)   // 132608 shorts = 265216 B

// LDS layout (bytes). Regions reuse the P area across phases.
#define P_STRIDE 676          // ushorts/row (>= KA, mult of 4)
#define LDS_AG 0              // A_gru [16] rows, stride 328 B
#define LDS_GATES 8192        // gates [16] rows, stride 520 B
#define LDS_AU 17024          // A_u [16] rows, stride 200 B
#define LDS_U 0               // u_lds [16][66] f32
#define LDS_BYTES 21632

__device__ __forceinline__ ushort f2u(float x) {
    __hip_bfloat16 b = __float2bfloat16(x);
    ushort u; __builtin_memcpy(&u, &b, 2); return u;
}
__device__ __forceinline__ float u2f(uint u) {
    union { uint x; float f; } c; c.x = u << 16; return c.f;
}
__device__ __forceinline__ uint pk2(float a, float b) {
    return (uint)f2u(a) | ((uint)f2u(b) << 16);
}
__device__ __forceinline__ float sigm(float x) { return 1.f / (1.f + __expf(-x)); }
// A-fragment: two ds_read_b64; elems 0-3 = kk, 4-7 = kk+16
__device__ __forceinline__ short8 lda(const char* base, int row, int strideB, int s, int g) {
    const char* p = base + row * strideB + s * 64 + g * 8;
    union { short8 v; uint2 q[2]; } u;
    u.q[0] = *(const uint2*)p;
    u.q[1] = *(const uint2*)(p + 32);
    return u.v;
}

// ---------------- prep: build B-fragment tables ----------------
__global__ __launch_bounds__(256) void prep_kernel(
    const float* __restrict__ he_w2, const float* __restrict__ he_b2,
    const float* __restrict__ ha_w2, const float* __restrict__ ha_b2,
    const float* __restrict__ fc1_own_w, const float* __restrict__ fc1_own_b,
    const float* __restrict__ agent_id_emb, const float* __restrict__ action_id_emb,
    const float* __restrict__ gru_w_ih, const float* __restrict__ gru_w_hh,
    const float* __restrict__ gru_b_ih, const float* __restrict__ gru_b_hh,
    const float* __restrict__ fc2_w, const float* __restrict__ fc2_b,
    ushort* __restrict__ ws)
{
    const int GE = KSE * 4, GA = KSA * 4, GG = KSG * 16, GU = KSU * 5;
    const int total = (GE + GA + GG + GU) * 64;
    int idx = blockIdx.x * 256 + threadIdx.x;
    if (idx >= total) return;
    int grp = idx >> 6, lane = idx & 63;
    int g = lane >> 4, col16 = lane & 15;
    int table, s, t, slot;
    if (grp < GE)           { table = 0; int q = grp;            s = q / 4;  t = q % 4;  slot = q * 64 + lane; }
    else if (grp < GE + GA) { table = 1; int q = grp - GE;       s = q / 4;  t = q % 4;  slot = q * 64 + lane; }
    else if (grp < GE + GA + GG) { table = 2; int q = grp - GE - GA; s = q / 16; t = q % 16; slot = q * 64 + lane; }
    else                    { table = 3; int q = grp - GE - GA - GG; s = q / 5; t = q % 5; slot = q * 64 + lane; }
    const int j = t * 16 + col16;
    ushort out[8];
    #pragma unroll
    for (int e = 0; e < 8; ++e) {
        int kk = 32 * s + 4 * g + (e & 3) + 16 * (e >> 2);
        float v = 0.f;
        if (table == 0) {
            if (kk < 576)      { int f = kk >> 6, k = kk & 63; v = he_w2[k * EW2 + f * HD + j]; }
            else if (kk < 585) { int f = kk - 576; v = he_b2[f * HD + j]; }
            else if (kk < 601) { int f = kk - 585; v = fc1_own_w[f * HD + j]; }
            else if (kk == 601){ v = fc1_own_b[j]; }
            else if (kk < 610) { int a = kk - 602; v = agent_id_emb[a * HD + j]; }
            else if (kk < 624) { int a = kk - 610; v = action_id_emb[a * HD + j]; }
        } else if (table == 1) {
            if (kk < 640)      { int f = kk >> 6, k = kk & 63; v = ha_w2[k * AW2 + f * HD + j]; }
            else if (kk < 650) { int f = kk - 640; v = ha_b2[f * HD + j]; }
        } else if (table == 2) {
            int gb = j >> 6, c = j & 63;
            if (gb <= 1) {
                int jj = gb * 64 + c;
                if (kk < 64)        v = gru_w_ih[jj * HD + kk];
                else if (kk < 128)  v = gru_w_hh[jj * HD + kk - 64];
                else if (kk == 128) v = gru_b_ih[jj] + gru_b_hh[jj];
            } else if (gb == 2) {
                int jj = 128 + c;
                if (kk < 64)        v = gru_w_ih[jj * HD + kk];
                else if (kk == 128) v = gru_b_ih[jj];
            } else {
                int jj = 128 + c;
                if (kk >= 64 && kk < 128) v = gru_w_hh[jj * HD + kk - 64];
                else if (kk == 128)       v = gru_b_hh[jj];
            }
        } else {
            if (j < 64) {
                if (kk < 64)       v = he_w2[j * EW2 + 576 + kk];
                else if (kk == 64) v = he_w2[j * EW2 + 640];
            } else if (j < 70) {
                int o = j - 64;
                if (kk < 64)       v = fc2_w[kk * 6 + o];
                else if (kk == 64) v = fc2_b[o];
            } else if (j == 70) {
                if (kk < 64)       v = he_b2[576 + kk];
                else if (kk == 64) v = he_b2[640];
            }
        }
        out[e] = f2u(v);
    }
    ushort* dst = ws + ((table == 0) ? BE_OFF : (table == 1) ? BA_OFF : (table == 2) ? BG_OFF : BU_OFF);
    *(short8*)(dst + slot * 8) = *(short8*)out;
}

// ---------------- main: fused, 4 waves / 16 rows; VGPR forced to the 64-reg occupancy step ----------------
__global__ __launch_bounds__(256, 4) void agent_kernel(
    const float* __restrict__ own_feats,
    const float* __restrict__ enemy_feats,
    const float* __restrict__ ally_feats,
    const float* __restrict__ hidden_state,
    const int*  __restrict__ agent_idx,
    const int*  __restrict__ last_act_idx,
    const float* __restrict__ he_w1, const float* __restrict__ he_b1,
    const float* __restrict__ ha_w1, const float* __restrict__ ha_b1,
    const ushort* __restrict__ ws,
    float* __restrict__ out_q, float* __restrict__ out_hh)
{
    __shared__ __align__(16) char smem[LDS_BYTES];
    const int tid  = threadIdx.x;
    const int lane = tid & 63;
    const int wv   = tid >> 6;
    const int n0   = blockIdx.x * 16;
    const int arow = lane & 15;
    const int g    = lane >> 4;
    ushort* P = (ushort*)smem;

    // ===== Phase 1: enemy P-build (wave-private rows 4wv..4wv+3) =====
    {
        float w1[E_FEAT];
        #pragma unroll
        for (int f = 0; f < E_FEAT; ++f) w1[f] = he_w1[f * HD + lane];
        const float b1 = he_b1[lane];
        #pragma unroll
        for (int rr = 0; rr < 4; ++rr) {
            const int row = wv * 4 + rr, n = n0 + row;
            const float* efb = enemy_feats + (size_t)n * (N_EN * E_FEAT);
            float pf[E_FEAT], sf[E_FEAT];
            #pragma unroll
            for (int f = 0; f < E_FEAT; ++f) { pf[f] = 0.f; sf[f] = 0.f; }
            #pragma unroll
            for (int e = 0; e < N_EN; ++e) {
                float ef[E_FEAT];
                #pragma unroll
                for (int f = 0; f < E_FEAT; ++f) ef[f] = efb[e * E_FEAT + f];
                float acc = b1;
                #pragma unroll
                for (int f = 0; f < E_FEAT; ++f) acc += ef[f] * w1[f];
                const float r = fmaxf(acc, 0.f);
                #pragma unroll
                for (int f = 0; f < E_FEAT; ++f) { pf[f] += r * ef[f]; sf[f] += ef[f]; }
            }
            ushort* Pr = P + row * P_STRIDE;
            #pragma unroll
            for (int f = 0; f < E_FEAT; ++f) Pr[f * HD + lane] = f2u(pf[f]);
            if (lane == 0) {
                #pragma unroll
                for (int f = 0; f < E_FEAT; ++f) Pr[576 + f] = f2u(sf[f]);
                Pr[601] = 0x3F80;
            }
            if (lane < OWN_FEAT) Pr[585 + lane] = f2u(own_feats[(size_t)n * OWN_FEAT + lane]);
            const int ai = agent_idx[n], la = last_act_idx[n];
            if (lane < 8)      Pr[602 + lane] = (lane == ai) ? 0x3F80 : 0;
            if (lane < N_ACT)  Pr[610 + lane] = (lane == la) ? 0x3F80 : 0;
            if (lane < 16)     Pr[624 + lane] = 0;
        }
    }
    __syncthreads();

    // ===== Phase 2: enemy GEMM (bounded unroll to limit in-flight b-loads) =====
    f32x4 accE = {0.f, 0.f, 0.f, 0.f};
    #pragma unroll 5
    for (int s = 0; s < KSE; ++s) {
        short8 b = *(const short8*)(ws + BE_OFF + ((size_t)(s * 4 + wv) * 64 + lane) * 8);
        short8 a = lda(smem, arow, P_STRIDE * 2, s, g);
        accE = __builtin_amdgcn_mfma_f32_16x16x32_bf16(a, b, accE, 0, 0, 0);
    }
    __syncthreads();

    // ===== Phase 3: ally P-build =====
    {
        float w1[A_FEAT];
        #pragma unroll
        for (int f = 0; f < A_FEAT; ++f) w1[f] = ha_w1[f * HD + lane];
        const float b1 = ha_b1[lane];
        #pragma unroll
        for (int rr = 0; rr < 4; ++rr) {
            const int row = wv * 4 + rr, n = n0 + row;
            const float* afb = ally_feats + (size_t)n * (N_AL * A_FEAT);
            float pf[A_FEAT], sf[A_FEAT];
            #pragma unroll
            for (int f = 0; f < A_FEAT; ++f) { pf[f] = 0.f; sf[f] = 0.f; }
            #pragma unroll
            for (int e = 0; e < N_AL; ++e) {
                float af[A_FEAT];
                #pragma unroll
                for (int f = 0; f < A_FEAT; ++f) af[f] = afb[e * A_FEAT + f];
                float acc = b1;
                #pragma unroll
                for (int f = 0; f < A_FEAT; ++f) acc += af[f] * w1[f];
                const float r = fmaxf(acc, 0.f);
                #pragma unroll
                for (int f = 0; f < A_FEAT; ++f) { pf[f] += r * af[f]; sf[f] += af[f]; }
            }
            ushort* Pr = P + row * P_STRIDE;
            #pragma unroll
            for (int f = 0; f < A_FEAT; ++f) Pr[f * HD + lane] = f2u(pf[f]);
            if (lane == 0) {
                #pragma unroll
                for (int f = 0; f < A_FEAT; ++f) Pr[640 + f] = f2u(sf[f]);
            }
            if (lane < 22) Pr[650 + lane] = 0;
        }
    }
    __syncthreads();

    // ===== Phase 4: ally GEMM (bounded unroll) =====
    #pragma unroll 7
    for (int s = 0; s < KSA; ++s) {
        short8 b = *(const short8*)(ws + BA_OFF + ((size_t)(s * 4 + wv) * 64 + lane) * 8);
        short8 a = lda(smem, arow, P_STRIDE * 2, s, g);
        accE = __builtin_amdgcn_mfma_f32_16x16x32_bf16(a, b, accE, 0, 0, 0);
    }
    __syncthreads();

    // ===== Phase 5: stage A_gru = [x | h | 1 | 0] =====
    float4 h4s;   // kept for phase 7 (same thread mapping)
    #pragma unroll
    for (int j = 0; j < 4; ++j) {
        const int m = g * 4 + j;
        *(ushort*)(smem + LDS_AG + m * 328 + (wv * 16 + arow) * 2) = f2u(fmaxf(accE[j], 0.f));
    }
    {
        const int row = tid >> 4, c4 = (tid & 15) * 4;
        h4s = *(const float4*)(hidden_state + (size_t)(n0 + row) * HD + c4);
        char* p = smem + LDS_AG + row * 328 + (64 + c4) * 2;
        *(uint*)p       = pk2(h4s.x, h4s.y);
        *(uint*)(p + 4) = pk2(h4s.z, h4s.w);
        if (tid < 16) *(ushort*)(smem + LDS_AG + tid * 328 + 128 * 2) = 0x3F80;
        for (int i = tid; i < 16 * 31; i += 256) {
            int r2 = i / 31, c = 129 + i % 31;
            *(ushort*)(smem + LDS_AG + r2 * 328 + c * 2) = 0;
        }
    }
    __syncthreads();

    // ===== Phase 6: GRU GEMM (N=256) =====
    {
        f32x4 accG[4] = {{0.f,0.f,0.f,0.f},{0.f,0.f,0.f,0.f},{0.f,0.f,0.f,0.f},{0.f,0.f,0.f,0.f}};
        #pragma unroll
        for (int s = 0; s < KSG; ++s) {
            short8 a = lda(smem + LDS_AG, arow, 328, s, g);
            #pragma unroll
            for (int tt = 0; tt < 4; ++tt) {
                const int t = wv * 4 + tt;
                short8 b = *(const short8*)(ws + BG_OFF + ((size_t)(s * 16 + t) * 64 + lane) * 8);
                accG[tt] = __builtin_amdgcn_mfma_f32_16x16x32_bf16(a, b, accG[tt], 0, 0, 0);
            }
        }
        #pragma unroll
        for (int tt = 0; tt < 4; ++tt)
            #pragma unroll
            for (int j = 0; j < 4; ++j) {
                const int m = g * 4 + j, jc = (wv * 4 + tt) * 16 + arow;
                *(ushort*)(smem + LDS_GATES + m * 520 + jc * 2) = f2u(accG[tt][j]);
            }
    }
    __syncthreads();

    // ===== Phase 7: pointwise GRU + stage A_u (h reused from phase 5) =====
    {
        const int row = tid >> 4, c4 = (tid & 15) * 4;
        const char* gb = smem + LDS_GATES + row * 520;
        uint2 rv = *(const uint2*)(gb + c4 * 2);
        uint2 zv = *(const uint2*)(gb + 128 + c4 * 2);
        uint2 iv = *(const uint2*)(gb + 256 + c4 * 2);
        uint2 nv = *(const uint2*)(gb + 384 + c4 * 2);
        float hr[4] = {u2f(rv.x & 0xffffu), u2f(rv.x >> 16), u2f(rv.y & 0xffffu), u2f(rv.y >> 16)};
        float hz[4] = {u2f(zv.x & 0xffffu), u2f(zv.x >> 16), u2f(zv.y & 0xffffu), u2f(zv.y >> 16)};
        float hi[4] = {u2f(iv.x & 0xffffu), u2f(iv.x >> 16), u2f(iv.y & 0xffffu), u2f(iv.y >> 16)};
        float hn[4] = {u2f(nv.x & 0xffffu), u2f(nv.x >> 16), u2f(nv.y & 0xffffu), u2f(nv.y >> 16)};
        float hcur[4] = {h4s.x, h4s.y, h4s.z, h4s.w};
        float hh[4];
        #pragma unroll
        for (int cc = 0; cc < 4; ++cc) {
            const float r = sigm(hr[cc]);
            const float z = sigm(hz[cc]);
            const float nng = tanhf(hi[cc] + r * hn[cc]);
            hh[cc] = (1.f - z) * nng + z * hcur[cc];
        }
        *(float4*)(out_hh + (size_t)(n0 + row) * HD + c4) = make_float4(hh[0], hh[1], hh[2], hh[3]);
        char* p = smem + LDS_AU + row * 200 + c4 * 2;
        *(uint*)p       = pk2(hh[0], hh[1]);
        *(uint*)(p + 4) = pk2(hh[2], hh[3]);
        if (tid < 16) *(ushort*)(smem + LDS_AU + tid * 200 + 64 * 2) = 0x3F80;
        for (int i = tid; i < 16 * 31; i += 256) {
            int r2 = i / 31, c = 65 + i % 31;
            *(ushort*)(smem + LDS_AU + r2 * 200 + c * 2) = 0;
        }
    }
    __syncthreads();

    // ===== Phase 8: u-GEMM (N=80) =====
    {
        f32x4 accU = {0.f, 0.f, 0.f, 0.f};
        f32x4 accQ = {0.f, 0.f, 0.f, 0.f};
        #pragma unroll
        for (int s = 0; s < KSU; ++s) {
            short8 a = lda(smem + LDS_AU, arow, 200, s, g);
            short8 b = *(const short8*)(ws + BU_OFF + ((size_t)(s * 5 + wv) * 64 + lane) * 8);
            accU = __builtin_amdgcn_mfma_f32_16x16x32_bf16(a, b, accU, 0, 0, 0);
            if (wv == 0) {
                short8 b2 = *(const short8*)(ws + BU_OFF + ((size_t)(s * 5 + 4) * 64 + lane) * 8);
                accQ = __builtin_amdgcn_mfma_f32_16x16x32_bf16(a, b2, accQ, 0, 0, 0);
            }
        }
        float* uld = (float*)(smem + LDS_U);
        #pragma unroll
        for (int j = 0; j < 4; ++j) {
            const int m = g * 4 + j;
            uld[m * 66 + wv * 16 + arow] = accU[j];
        }
        if (wv == 0) {
            #pragma unroll
            for (int j = 0; j < 4; ++j) {
                const int m = g * 4 + j;
                if (arow < 6)       out_q[(size_t)(n0 + m) * N_ACT + arow] = accQ[j];
                else if (arow == 6) uld[m * 66 + 64] = accQ[j];
            }
        }
    }
    __syncthreads();

    // ===== Phase 9: attack head (r recomputed; wave wv owns rows 4wv..4wv+3) =====
    {
        float w1[E_FEAT];
        #pragma unroll
        for (int f = 0; f < E_FEAT; ++f) w1[f] = he_w1[f * HD + lane];
        const float b1 = he_b1[lane];
        const float* uld = (const float*)(smem + LDS_U);
        #pragma unroll
        for (int rr = 0; rr < 4; ++rr) {
            const int row = wv * 4 + rr, n = n0 + row;
            const float uk = uld[row * 66 + lane];
            const float ct = uld[row * 66 + 64];
            const float* efb = enemy_feats + (size_t)n * (N_EN * E_FEAT);
            float p[N_EN];
            #pragma unroll
            for (int e = 0; e < N_EN; ++e) {
                float acc = b1;
                #pragma unroll
                for (int f = 0; f < E_FEAT; ++f) acc += efb[e * E_FEAT + f] * w1[f];
                p[e] = fmaxf(acc, 0.f) * uk;
            }
            #pragma unroll
            for (int o = 1; o < 64; o <<= 1) {
                #pragma unroll
                for (int e = 0; e < N_EN; ++e) p[e] += __shfl_xor(p[e], o);
            }
            if (lane < N_EN) {
                float pv = p[0];
                #pragma unroll
                for (int e = 1; e < N_EN; ++e) if (lane == e) pv = p[e];
                out_q[(size_t)n * N_ACT + 6 + lane] = pv + ct;
            }
        }
    }
}

extern "C" void kernel_launch(void* const* d_in, const int* in_sizes, int n_in,
                              void* d_out, int out_size, void* d_ws, size_t ws_size,
                              hipStream_t stream) {
    const float* own_feats    = (const float*)d_in[0];
    const float* enemy_feats  = (const float*)d_in[1];
    const float* ally_feats   = (const float*)d_in[2];
    const float* hidden_state = (const float*)d_in[3];
    const int*  agent_idx     = (const int*)d_in[4];
    const int*  last_act      = (const int*)d_in[5];
    const float* fc1_own_w = (const float*)d_in[7];
    const float* fc1_own_b = (const float*)d_in[8];
    const float* agent_id_emb  = (const float*)d_in[9];
    const float* action_id_emb = (const float*)d_in[10];
    const float* he_w1 = (const float*)d_in[11];
    const float* he_b1 = (const float*)d_in[12];
    const float* he_w2 = (const float*)d_in[13];
    const float* he_b2 = (const float*)d_in[14];
    const float* ha_w1 = (const float*)d_in[15];
    const float* ha_b1 = (const float*)d_in[16];
    const float* ha_w2 = (const float*)d_in[17];
    const float* ha_b2 = (const float*)d_in[18];
    const float* gru_w_ih = (const float*)d_in[19];
    const float* gru_w_hh = (const float*)d_in[20];
    const float* gru_b_ih = (const float*)d_in[21];
    const float* gru_b_hh = (const float*)d_in[22];
    const float* fc2_w = (const float*)d_in[23];
    const float* fc2_b = (const float*)d_in[24];

    const int R = in_sizes[0] / OWN_FEAT;  // 32768
    ushort* ws = (ushort*)d_ws;
    float* out_q  = (float*)d_out;
    float* out_hh = out_q + (size_t)R * N_ACT;

    prep_kernel<<<65, 256, 0, stream>>>(
        he_w2, he_b2, ha_w2, ha_b2, fc1_own_w, fc1_own_b,
        agent_id_emb, action_id_emb, gru_w_ih, gru_w_hh, gru_b_ih, gru_b_hh,
        fc2_w, fc2_b, ws);

    agent_kernel<<<R / 16, 256, 0, stream>>>(
        own_feats, enemy_feats, ally_feats, hidden_state, agent_idx, last_act,
        he_w1, he_b1, ha_w1, ha_b1, ws, out_q, out_hh);
}

// Round 16
// 93.207 us; speedup vs baseline: 1.8241x; 1.0431x over previous
//
#include <hip/hip_runtime.h>
#include <hip/hip_bf16.h>

typedef short short8 __attribute__((ext_vector_type(8)));
typedef float f32x4 __attribute__((ext_vector_type(4)));

#define HD 64
#define N_EN 8
#define N_AL 7
#define E_FEAT 9
#define A_FEAT 10
#define OWN_FEAT 16
#define N_ACT 14
#define EW2 641
#define AW2 640

// GEMM K sizes (padded to multiples of 32)
#define KSE 20   // enemy: K=640
#define KSA 21   // ally : K=672
#define KSG 5    // gru  : K=160
#define KSU 3    // u    : K=96

// B-fragment tables in ws (ushort units)
#define BE_OFF 0
#define BE_CNT (KSE*4*64*8)
#define BA_OFF (BE_OFF+BE_CNT)
#define BA_CNT (KSA*4*64*8)
#define BG_OFF (BA_OFF+BA_CNT)
#define BG_CNT (KSG*16*64*8)
#define BU_OFF (BG_OFF+BG_CNT)
#define BU_CNT (KSU*5*64*8)
#define WS_SHORTS (BU_OFF+BU_CNT)   // 132608 shorts = 265216 B

// LDS layout (bytes). Regions reuse the P area across phases.
#define P_STRIDE 676          // ushorts/row (>= KA, mult of 4)
#define LDS_AG 0              // A_gru [16] rows, stride 328 B
#define LDS_GATES 8192        // gates [16] rows, stride 520 B
#define LDS_AU 17024          // A_u [16] rows, stride 200 B
#define LDS_U 0               // u_lds [16][66] f32
#define LDS_BYTES 21632

__device__ __forceinline__ ushort f2u(float x) {
    __hip_bfloat16 b = __float2bfloat16(x);
    ushort u; __builtin_memcpy(&u, &b, 2); return u;
}
__device__ __forceinline__ float u2f(uint u) {
    union { uint x; float f; } c; c.x = u << 16; return c.f;
}
__device__ __forceinline__ uint pk2(float a, float b) {
    return (uint)f2u(a) | ((uint)f2u(b) << 16);
}
__device__ __forceinline__ float sigm(float x) { return 1.f / (1.f + __expf(-x)); }
// A-fragment: two ds_read_b64; elems 0-3 = kk, 4-7 = kk+16
__device__ __forceinline__ short8 lda(const char* base, int row, int strideB, int s, int g) {
    const char* p = base + row * strideB + s * 64 + g * 8;
    union { short8 v; uint2 q[2]; } u;
    u.q[0] = *(const uint2*)p;
    u.q[1] = *(const uint2*)(p + 32);
    return u.v;
}

// ---------------- prep: build B-fragment tables ----------------
__global__ __launch_bounds__(256) void prep_kernel(
    const float* __restrict__ he_w2, const float* __restrict__ he_b2,
    const float* __restrict__ ha_w2, const float* __restrict__ ha_b2,
    const float* __restrict__ fc1_own_w, const float* __restrict__ fc1_own_b,
    const float* __restrict__ agent_id_emb, const float* __restrict__ action_id_emb,
    const float* __restrict__ gru_w_ih, const float* __restrict__ gru_w_hh,
    const float* __restrict__ gru_b_ih, const float* __restrict__ gru_b_hh,
    const float* __restrict__ fc2_w, const float* __restrict__ fc2_b,
    ushort* __restrict__ ws)
{
    const int GE = KSE * 4, GA = KSA * 4, GG = KSG * 16, GU = KSU * 5;
    const int total = (GE + GA + GG + GU) * 64;
    int idx = blockIdx.x * 256 + threadIdx.x;
    if (idx >= total) return;
    int grp = idx >> 6, lane = idx & 63;
    int g = lane >> 4, col16 = lane & 15;
    int table, s, t, slot;
    if (grp < GE)           { table = 0; int q = grp;            s = q / 4;  t = q % 4;  slot = q * 64 + lane; }
    else if (grp < GE + GA) { table = 1; int q = grp - GE;       s = q / 4;  t = q % 4;  slot = q * 64 + lane; }
    else if (grp < GE + GA + GG) { table = 2; int q = grp - GE - GA; s = q / 16; t = q % 16; slot = q * 64 + lane; }
    else                    { table = 3; int q = grp - GE - GA - GG; s = q / 5; t = q % 5; slot = q * 64 + lane; }
    const int j = t * 16 + col16;
    ushort out[8];
    #pragma unroll
    for (int e = 0; e < 8; ++e) {
        int kk = 32 * s + 4 * g + (e & 3) + 16 * (e >> 2);
        float v = 0.f;
        if (table == 0) {
            if (kk < 576)      { int f = kk >> 6, k = kk & 63; v = he_w2[k * EW2 + f * HD + j]; }
            else if (kk < 585) { int f = kk - 576; v = he_b2[f * HD + j]; }
            else if (kk < 601) { int f = kk - 585; v = fc1_own_w[f * HD + j]; }
            else if (kk == 601){ v = fc1_own_b[j]; }
            else if (kk < 610) { int a = kk - 602; v = agent_id_emb[a * HD + j]; }
            else if (kk < 624) { int a = kk - 610; v = action_id_emb[a * HD + j]; }
        } else if (table == 1) {
            if (kk < 640)      { int f = kk >> 6, k = kk & 63; v = ha_w2[k * AW2 + f * HD + j]; }
            else if (kk < 650) { int f = kk - 640; v = ha_b2[f * HD + j]; }
        } else if (table == 2) {
            int gb = j >> 6, c = j & 63;
            if (gb <= 1) {
                int jj = gb * 64 + c;
                if (kk < 64)        v = gru_w_ih[jj * HD + kk];
                else if (kk < 128)  v = gru_w_hh[jj * HD + kk - 64];
                else if (kk == 128) v = gru_b_ih[jj] + gru_b_hh[jj];
            } else if (gb == 2) {
                int jj = 128 + c;
                if (kk < 64)        v = gru_w_ih[jj * HD + kk];
                else if (kk == 128) v = gru_b_ih[jj];
            } else {
                int jj = 128 + c;
                if (kk >= 64 && kk < 128) v = gru_w_hh[jj * HD + kk - 64];
                else if (kk == 128)       v = gru_b_hh[jj];
            }
        } else {
            if (j < 64) {
                if (kk < 64)       v = he_w2[j * EW2 + 576 + kk];
                else if (kk == 64) v = he_w2[j * EW2 + 640];
            } else if (j < 70) {
                int o = j - 64;
                if (kk < 64)       v = fc2_w[kk * 6 + o];
                else if (kk == 64) v = fc2_b[o];
            } else if (j == 70) {
                if (kk < 64)       v = he_b2[576 + kk];
                else if (kk == 64) v = he_b2[640];
            }
        }
        out[e] = f2u(v);
    }
    ushort* dst = ws + ((table == 0) ? BE_OFF : (table == 1) ? BA_OFF : (table == 2) ? BG_OFF : BU_OFF);
    *(short8*)(dst + slot * 8) = *(short8*)out;
}

// ---------------- main: fused, 4 waves / 16 rows; 64-VGPR target, spill-free ----------------
__global__ __launch_bounds__(256, 4) void agent_kernel(
    const float* __restrict__ own_feats,
    const float* __restrict__ enemy_feats,
    const float* __restrict__ ally_feats,
    const float* __restrict__ hidden_state,
    const int*  __restrict__ agent_idx,
    const int*  __restrict__ last_act_idx,
    const float* __restrict__ he_w1, const float* __restrict__ he_b1,
    const float* __restrict__ ha_w1, const float* __restrict__ ha_b1,
    const ushort* __restrict__ ws,
    float* __restrict__ out_q, float* __restrict__ out_hh)
{
    __shared__ __align__(16) char smem[LDS_BYTES];
    const int tid  = threadIdx.x;
    const int lane = tid & 63;
    const int wv   = tid >> 6;
    const int n0   = blockIdx.x * 16;
    const int arow = lane & 15;
    const int g    = lane >> 4;
    ushort* P = (ushort*)smem;

    // ===== Phase 1: enemy P-build (wave-private rows 4wv..4wv+3); sef lane-parallel =====
    {
        float w1[E_FEAT];
        #pragma unroll
        for (int f = 0; f < E_FEAT; ++f) w1[f] = he_w1[f * HD + lane];
        const float b1 = he_b1[lane];
        #pragma unroll
        for (int rr = 0; rr < 4; ++rr) {
            const int row = wv * 4 + rr, n = n0 + row;
            const float* efb = enemy_feats + (size_t)n * (N_EN * E_FEAT);
            float pf[E_FEAT];
            #pragma unroll
            for (int f = 0; f < E_FEAT; ++f) pf[f] = 0.f;
            #pragma unroll
            for (int e = 0; e < N_EN; ++e) {
                float ef[E_FEAT];
                #pragma unroll
                for (int f = 0; f < E_FEAT; ++f) ef[f] = efb[e * E_FEAT + f];
                float acc = b1;
                #pragma unroll
                for (int f = 0; f < E_FEAT; ++f) acc += ef[f] * w1[f];
                const float r = fmaxf(acc, 0.f);
                #pragma unroll
                for (int f = 0; f < E_FEAT; ++f) pf[f] += r * ef[f];
            }
            ushort* Pr = P + row * P_STRIDE;
            #pragma unroll
            for (int f = 0; f < E_FEAT; ++f) Pr[f * HD + lane] = f2u(pf[f]);
            if (lane < E_FEAT) {            // sef lane-parallel (no per-lane sf[9] array)
                float sv = 0.f;
                #pragma unroll
                for (int e = 0; e < N_EN; ++e) sv += efb[e * E_FEAT + lane];
                Pr[576 + lane] = f2u(sv);
            }
            if (lane == 20) Pr[601] = 0x3F80;
            if (lane < OWN_FEAT) Pr[585 + lane] = f2u(own_feats[(size_t)n * OWN_FEAT + lane]);
            const int ai = agent_idx[n], la = last_act_idx[n];
            if (lane < 8)      Pr[602 + lane] = (lane == ai) ? 0x3F80 : 0;
            if (lane < N_ACT)  Pr[610 + lane] = (lane == la) ? 0x3F80 : 0;
            if (lane < 16)     Pr[624 + lane] = 0;
        }
    }
    __syncthreads();

    // ===== Phase 2: enemy GEMM (bounded unroll) =====
    f32x4 accE = {0.f, 0.f, 0.f, 0.f};
    #pragma unroll 5
    for (int s = 0; s < KSE; ++s) {
        short8 b = *(const short8*)(ws + BE_OFF + ((size_t)(s * 4 + wv) * 64 + lane) * 8);
        short8 a = lda(smem, arow, P_STRIDE * 2, s, g);
        accE = __builtin_amdgcn_mfma_f32_16x16x32_bf16(a, b, accE, 0, 0, 0);
    }
    __syncthreads();

    // ===== Phase 3: ally P-build; saf lane-parallel =====
    {
        float w1[A_FEAT];
        #pragma unroll
        for (int f = 0; f < A_FEAT; ++f) w1[f] = ha_w1[f * HD + lane];
        const float b1 = ha_b1[lane];
        #pragma unroll
        for (int rr = 0; rr < 4; ++rr) {
            const int row = wv * 4 + rr, n = n0 + row;
            const float* afb = ally_feats + (size_t)n * (N_AL * A_FEAT);
            float pf[A_FEAT];
            #pragma unroll
            for (int f = 0; f < A_FEAT; ++f) pf[f] = 0.f;
            #pragma unroll
            for (int e = 0; e < N_AL; ++e) {
                float af[A_FEAT];
                #pragma unroll
                for (int f = 0; f < A_FEAT; ++f) af[f] = afb[e * A_FEAT + f];
                float acc = b1;
                #pragma unroll
                for (int f = 0; f < A_FEAT; ++f) acc += af[f] * w1[f];
                const float r = fmaxf(acc, 0.f);
                #pragma unroll
                for (int f = 0; f < A_FEAT; ++f) pf[f] += r * af[f];
            }
            ushort* Pr = P + row * P_STRIDE;
            #pragma unroll
            for (int f = 0; f < A_FEAT; ++f) Pr[f * HD + lane] = f2u(pf[f]);
            if (lane < A_FEAT) {            // saf lane-parallel
                float sv = 0.f;
                #pragma unroll
                for (int e = 0; e < N_AL; ++e) sv += afb[e * A_FEAT + lane];
                Pr[640 + lane] = f2u(sv);
            }
            if (lane < 22) Pr[650 + lane] = 0;
        }
    }
    __syncthreads();

    // ===== Phase 4: ally GEMM (bounded unroll) =====
    #pragma unroll 7
    for (int s = 0; s < KSA; ++s) {
        short8 b = *(const short8*)(ws + BA_OFF + ((size_t)(s * 4 + wv) * 64 + lane) * 8);
        short8 a = lda(smem, arow, P_STRIDE * 2, s, g);
        accE = __builtin_amdgcn_mfma_f32_16x16x32_bf16(a, b, accE, 0, 0, 0);
    }
    __syncthreads();

    // ===== Phase 5: stage A_gru = [x | h | 1 | 0] =====
    #pragma unroll
    for (int j = 0; j < 4; ++j) {
        const int m = g * 4 + j;
        *(ushort*)(smem + LDS_AG + m * 328 + (wv * 16 + arow) * 2) = f2u(fmaxf(accE[j], 0.f));
    }
    {
        const int row = tid >> 4, c4 = (tid & 15) * 4;
        float4 h4 = *(const float4*)(hidden_state + (size_t)(n0 + row) * HD + c4);
        char* p = smem + LDS_AG + row * 328 + (64 + c4) * 2;
        *(uint*)p       = pk2(h4.x, h4.y);
        *(uint*)(p + 4) = pk2(h4.z, h4.w);
        if (tid < 16) *(ushort*)(smem + LDS_AG + tid * 328 + 128 * 2) = 0x3F80;
        for (int i = tid; i < 16 * 31; i += 256) {
            int r2 = i / 31, c = 129 + i % 31;
            *(ushort*)(smem + LDS_AG + r2 * 328 + c * 2) = 0;
        }
    }
    __syncthreads();

    // ===== Phase 6: GRU GEMM (N=256) =====
    {
        f32x4 accG[4] = {{0.f,0.f,0.f,0.f},{0.f,0.f,0.f,0.f},{0.f,0.f,0.f,0.f},{0.f,0.f,0.f,0.f}};
        #pragma unroll
        for (int s = 0; s < KSG; ++s) {
            short8 a = lda(smem + LDS_AG, arow, 328, s, g);
            #pragma unroll
            for (int tt = 0; tt < 4; ++tt) {
                const int t = wv * 4 + tt;
                short8 b = *(const short8*)(ws + BG_OFF + ((size_t)(s * 16 + t) * 64 + lane) * 8);
                accG[tt] = __builtin_amdgcn_mfma_f32_16x16x32_bf16(a, b, accG[tt], 0, 0, 0);
            }
        }
        #pragma unroll
        for (int tt = 0; tt < 4; ++tt)
            #pragma unroll
            for (int j = 0; j < 4; ++j) {
                const int m = g * 4 + j, jc = (wv * 4 + tt) * 16 + arow;
                *(ushort*)(smem + LDS_GATES + m * 520 + jc * 2) = f2u(accG[tt][j]);
            }
    }
    __syncthreads();

    // ===== Phase 7: pointwise GRU + stage A_u (h reloaded — frees the carry regs) =====
    {
        const int row = tid >> 4, c4 = (tid & 15) * 4;
        const char* gb = smem + LDS_GATES + row * 520;
        uint2 rv = *(const uint2*)(gb + c4 * 2);
        uint2 zv = *(const uint2*)(gb + 128 + c4 * 2);
        uint2 iv = *(const uint2*)(gb + 256 + c4 * 2);
        uint2 nv = *(const uint2*)(gb + 384 + c4 * 2);
        float4 h4 = *(const float4*)(hidden_state + (size_t)(n0 + row) * HD + c4);
        float hr[4] = {u2f(rv.x & 0xffffu), u2f(rv.x >> 16), u2f(rv.y & 0xffffu), u2f(rv.y >> 16)};
        float hz[4] = {u2f(zv.x & 0xffffu), u2f(zv.x >> 16), u2f(zv.y & 0xffffu), u2f(zv.y >> 16)};
        float hi[4] = {u2f(iv.x & 0xffffu), u2f(iv.x >> 16), u2f(iv.y & 0xffffu), u2f(iv.y >> 16)};
        float hn[4] = {u2f(nv.x & 0xffffu), u2f(nv.x >> 16), u2f(nv.y & 0xffffu), u2f(nv.y >> 16)};
        float hcur[4] = {h4.x, h4.y, h4.z, h4.w};
        float hh[4];
        #pragma unroll
        for (int cc = 0; cc < 4; ++cc) {
            const float r = sigm(hr[cc]);
            const float z = sigm(hz[cc]);
            const float nng = tanhf(hi[cc] + r * hn[cc]);
            hh[cc] = (1.f - z) * nng + z * hcur[cc];
        }
        *(float4*)(out_hh + (size_t)(n0 + row) * HD + c4) = make_float4(hh[0], hh[1], hh[2], hh[3]);
        char* p = smem + LDS_AU + row * 200 + c4 * 2;
        *(uint*)p       = pk2(hh[0], hh[1]);
        *(uint*)(p + 4) = pk2(hh[2], hh[3]);
        if (tid < 16) *(ushort*)(smem + LDS_AU + tid * 200 + 64 * 2) = 0x3F80;
        for (int i = tid; i < 16 * 31; i += 256) {
            int r2 = i / 31, c = 65 + i % 31;
            *(ushort*)(smem + LDS_AU + r2 * 200 + c * 2) = 0;
        }
    }
    __syncthreads();

    // ===== Phase 8: u-GEMM (N=80) =====
    {
        f32x4 accU = {0.f, 0.f, 0.f, 0.f};
        f32x4 accQ = {0.f, 0.f, 0.f, 0.f};
        #pragma unroll
        for (int s = 0; s < KSU; ++s) {
            short8 a = lda(smem + LDS_AU, arow, 200, s, g);
            short8 b = *(const short8*)(ws + BU_OFF + ((size_t)(s * 5 + wv) * 64 + lane) * 8);
            accU = __builtin_amdgcn_mfma_f32_16x16x32_bf16(a, b, accU, 0, 0, 0);
            if (wv == 0) {
                short8 b2 = *(const short8*)(ws + BU_OFF + ((size_t)(s * 5 + 4) * 64 + lane) * 8);
                accQ = __builtin_amdgcn_mfma_f32_16x16x32_bf16(a, b2, accQ, 0, 0, 0);
            }
        }
        float* uld = (float*)(smem + LDS_U);
        #pragma unroll
        for (int j = 0; j < 4; ++j) {
            const int m = g * 4 + j;
            uld[m * 66 + wv * 16 + arow] = accU[j];
        }
        if (wv == 0) {
            #pragma unroll
            for (int j = 0; j < 4; ++j) {
                const int m = g * 4 + j;
                if (arow < 6)       out_q[(size_t)(n0 + m) * N_ACT + arow] = accQ[j];
                else if (arow == 6) uld[m * 66 + 64] = accQ[j];
            }
        }
    }
    __syncthreads();

    // ===== Phase 9: attack head (r recomputed; wave wv owns rows 4wv..4wv+3) =====
    {
        float w1[E_FEAT];
        #pragma unroll
        for (int f = 0; f < E_FEAT; ++f) w1[f] = he_w1[f * HD + lane];
        const float b1 = he_b1[lane];
        const float* uld = (const float*)(smem + LDS_U);
        #pragma unroll
        for (int rr = 0; rr < 4; ++rr) {
            const int row = wv * 4 + rr, n = n0 + row;
            const float uk = uld[row * 66 + lane];
            const float ct = uld[row * 66 + 64];
            const float* efb = enemy_feats + (size_t)n * (N_EN * E_FEAT);
            float p[N_EN];
            #pragma unroll
            for (int e = 0; e < N_EN; ++e) {
                float acc = b1;
                #pragma unroll
                for (int f = 0; f < E_FEAT; ++f) acc += efb[e * E_FEAT + f] * w1[f];
                p[e] = fmaxf(acc, 0.f) * uk;
            }
            #pragma unroll
            for (int o = 1; o < 64; o <<= 1) {
                #pragma unroll
                for (int e = 0; e < N_EN; ++e) p[e] += __shfl_xor(p[e], o);
            }
            if (lane < N_EN) {
                float pv = p[0];
                #pragma unroll
                for (int e = 1; e < N_EN; ++e) if (lane == e) pv = p[e];
                out_q[(size_t)n * N_ACT + 6 + lane] = pv + ct;
            }
        }
    }
}

extern "C" void kernel_launch(void* const* d_in, const int* in_sizes, int n_in,
                              void* d_out, int out_size, void* d_ws, size_t ws_size,
                              hipStream_t stream) {
    const float* own_feats    = (const float*)d_in[0];
    const float* enemy_feats  = (const float*)d_in[1];
    const float* ally_feats   = (const float*)d_in[2];
    const float* hidden_state = (const float*)d_in[3];
    const int*  agent_idx     = (const int*)d_in[4];
    const int*  last_act      = (const int*)d_in[5];
    const float* fc1_own_w = (const float*)d_in[7];
    const float* fc1_own_b = (const float*)d_in[8];
    const float* agent_id_emb  = (const float*)d_in[9];
    const float* action_id_emb = (const float*)d_in[10];
    const float* he_w1 = (const float*)d_in[11];
    const float* he_b1 = (const float*)d_in[12];
    const float* he_w2 = (const float*)d_in[13];
    const float* he_b2 = (const float*)d_in[14];
    const float* ha_w1 = (const float*)d_in[15];
    const float* ha_b1 = (const float*)d_in[16];
    const float* ha_w2 = (const float*)d_in[17];
    const float* ha_b2 = (const float*)d_in[18];
    const float* gru_w_ih = (const float*)d_in[19];
    const float* gru_w_hh = (const float*)d_in[20];
    const float* gru_b_ih = (const float*)d_in[21];
    const float* gru_b_hh = (const float*)d_in[22];
    const float* fc2_w = (const float*)d_in[23];
    const float* fc2_b = (const float*)d_in[24];

    const int R = in_sizes[0] / OWN_FEAT;  // 32768
    ushort* ws = (ushort*)d_ws;
    float* out_q  = (float*)d_out;
    float* out_hh = out_q + (size_t)R * N_ACT;

    prep_kernel<<<65, 256, 0, stream>>>(
        he_w2, he_b2, ha_w2, ha_b2, fc1_own_w, fc1_own_b,
        agent_id_emb, action_id_emb, gru_w_ih, gru_w_hh, gru_b_ih, gru_b_hh,
        fc2_w, fc2_b, ws);

    agent_kernel<<<R / 16, 256, 0, stream>>>(
        own_feats, enemy_feats, ally_feats, hidden_state, agent_idx, last_act,
        he_w1, he_b1, ha_w1, ha_b1, ws, out_q, out_hh);
}

// Round 17
// 91.592 us; speedup vs baseline: 1.8563x; 1.0176x over previous
//
#include <hip/hip_runtime.h>
#include <hip/hip_bf16.h>

typedef short short8 __attribute__((ext_vector_type(8)));
typedef float f32x4 __attribute__((ext_vector_type(4)));

#define HD 64
#define N_EN 8
#define N_AL 7
#define E_FEAT 9
#define A_FEAT 10
#define OWN_FEAT 16
#define N_ACT 14
#define EW2 641
#define AW2 640

// GEMM K sizes (padded to multiples of 32)
#define KSE 20   // enemy: K=640
#define KSA 21   // ally : K=672
#define KSG 5    // gru  : K=160
#define KSU 3    // u    : K=96

// B-fragment tables in ws (ushort units)
#define BE_OFF 0
#define BE_CNT (KSE*4*64*8)
#define BA_OFF (BE_OFF+BE_CNT)
#define BA_CNT (KSA*4*64*8)
#define BG_OFF (BA_OFF+BA_CNT)
#define BG_CNT (KSG*16*64*8)
#define BU_OFF (BG_OFF+BG_CNT)
#define BU_CNT (KSU*5*64*8)
#define WS_SHORTS (BU_OFF+BU_CNT)   // 132608 shorts = 265216 B

// LDS layout (bytes). Regions reuse the P area across phases.
#define P_STRIDE 676          // ushorts/row (>= KA, mult of 4)
#define LDS_AG 0              // A_gru [16] rows, stride 328 B
#define LDS_GATES 8192        // gates [16] rows, stride 520 B
#define LDS_AU 17024          // A_u [16] rows, stride 200 B
#define LDS_U 0               // u_lds [16][66] f32
#define LDS_BYTES 21632

__device__ __forceinline__ ushort f2u(float x) {
    __hip_bfloat16 b = __float2bfloat16(x);
    ushort u; __builtin_memcpy(&u, &b, 2); return u;
}
__device__ __forceinline__ float u2f(uint u) {
    union { uint x; float f; } c; c.x = u << 16; return c.f;
}
__device__ __forceinline__ uint pk2(float a, float b) {
    return (uint)f2u(a) | ((uint)f2u(b) << 16);
}
__device__ __forceinline__ float sigm(float x) { return 1.f / (1.f + __expf(-x)); }
// A-fragment: two ds_read_b64; elems 0-3 = kk, 4-7 = kk+16
__device__ __forceinline__ short8 lda(const char* base, int row, int strideB, int s, int g) {
    const char* p = base + row * strideB + s * 64 + g * 8;
    union { short8 v; uint2 q[2]; } u;
    u.q[0] = *(const uint2*)p;
    u.q[1] = *(const uint2*)(p + 32);
    return u.v;
}

// ---------------- prep: build B-fragment tables ----------------
__global__ __launch_bounds__(256) void prep_kernel(
    const float* __restrict__ he_w2, const float* __restrict__ he_b2,
    const float* __restrict__ ha_w2, const float* __restrict__ ha_b2,
    const float* __restrict__ fc1_own_w, const float* __restrict__ fc1_own_b,
    const float* __restrict__ agent_id_emb, const float* __restrict__ action_id_emb,
    const float* __restrict__ gru_w_ih, const float* __restrict__ gru_w_hh,
    const float* __restrict__ gru_b_ih, const float* __restrict__ gru_b_hh,
    const float* __restrict__ fc2_w, const float* __restrict__ fc2_b,
    ushort* __restrict__ ws)
{
    const int GE = KSE * 4, GA = KSA * 4, GG = KSG * 16, GU = KSU * 5;
    const int total = (GE + GA + GG + GU) * 64;
    int idx = blockIdx.x * 256 + threadIdx.x;
    if (idx >= total) return;
    int grp = idx >> 6, lane = idx & 63;
    int g = lane >> 4, col16 = lane & 15;
    int table, s, t, slot;
    if (grp < GE)           { table = 0; int q = grp;            s = q / 4;  t = q % 4;  slot = q * 64 + lane; }
    else if (grp < GE + GA) { table = 1; int q = grp - GE;       s = q / 4;  t = q % 4;  slot = q * 64 + lane; }
    else if (grp < GE + GA + GG) { table = 2; int q = grp - GE - GA; s = q / 16; t = q % 16; slot = q * 64 + lane; }
    else                    { table = 3; int q = grp - GE - GA - GG; s = q / 5; t = q % 5; slot = q * 64 + lane; }
    const int j = t * 16 + col16;
    ushort out[8];
    #pragma unroll
    for (int e = 0; e < 8; ++e) {
        int kk = 32 * s + 4 * g + (e & 3) + 16 * (e >> 2);
        float v = 0.f;
        if (table == 0) {
            if (kk < 576)      { int f = kk >> 6, k = kk & 63; v = he_w2[k * EW2 + f * HD + j]; }
            else if (kk < 585) { int f = kk - 576; v = he_b2[f * HD + j]; }
            else if (kk < 601) { int f = kk - 585; v = fc1_own_w[f * HD + j]; }
            else if (kk == 601){ v = fc1_own_b[j]; }
            else if (kk < 610) { int a = kk - 602; v = agent_id_emb[a * HD + j]; }
            else if (kk < 624) { int a = kk - 610; v = action_id_emb[a * HD + j]; }
        } else if (table == 1) {
            if (kk < 640)      { int f = kk >> 6, k = kk & 63; v = ha_w2[k * AW2 + f * HD + j]; }
            else if (kk < 650) { int f = kk - 640; v = ha_b2[f * HD + j]; }
        } else if (table == 2) {
            int gb = j >> 6, c = j & 63;
            if (gb <= 1) {
                int jj = gb * 64 + c;
                if (kk < 64)        v = gru_w_ih[jj * HD + kk];
                else if (kk < 128)  v = gru_w_hh[jj * HD + kk - 64];
                else if (kk == 128) v = gru_b_ih[jj] + gru_b_hh[jj];
            } else if (gb == 2) {
                int jj = 128 + c;
                if (kk < 64)        v = gru_w_ih[jj * HD + kk];
                else if (kk == 128) v = gru_b_ih[jj];
            } else {
                int jj = 128 + c;
                if (kk >= 64 && kk < 128) v = gru_w_hh[jj * HD + kk - 64];
                else if (kk == 128)       v = gru_b_hh[jj];
            }
        } else {
            if (j < 64) {
                if (kk < 64)       v = he_w2[j * EW2 + 576 + kk];
                else if (kk == 64) v = he_w2[j * EW2 + 640];
            } else if (j < 70) {
                int o = j - 64;
                if (kk < 64)       v = fc2_w[kk * 6 + o];
                else if (kk == 64) v = fc2_b[o];
            } else if (j == 70) {
                if (kk < 64)       v = he_b2[576 + kk];
                else if (kk == 64) v = he_b2[640];
            }
        }
        out[e] = f2u(v);
    }
    ushort* dst = ws + ((table == 0) ? BE_OFF : (table == 1) ? BA_OFF : (table == 2) ? BG_OFF : BU_OFF);
    *(short8*)(dst + slot * 8) = *(short8*)out;
}

// ---------------- main: fused, 4 waves / 16 rows; 64-VGPR, setprio on MFMA clusters ----------------
__global__ __launch_bounds__(256, 4) void agent_kernel(
    const float* __restrict__ own_feats,
    const float* __restrict__ enemy_feats,
    const float* __restrict__ ally_feats,
    const float* __restrict__ hidden_state,
    const int*  __restrict__ agent_idx,
    const int*  __restrict__ last_act_idx,
    const float* __restrict__ he_w1, const float* __restrict__ he_b1,
    const float* __restrict__ ha_w1, const float* __restrict__ ha_b1,
    const ushort* __restrict__ ws,
    float* __restrict__ out_q, float* __restrict__ out_hh)
{
    __shared__ __align__(16) char smem[LDS_BYTES];
    const int tid  = threadIdx.x;
    const int lane = tid & 63;
    const int wv   = tid >> 6;
    const int n0   = blockIdx.x * 16;
    const int arow = lane & 15;
    const int g    = lane >> 4;
    ushort* P = (ushort*)smem;

    // ===== Phase 1: enemy P-build (wave-private rows 4wv..4wv+3); sef lane-parallel =====
    {
        float w1[E_FEAT];
        #pragma unroll
        for (int f = 0; f < E_FEAT; ++f) w1[f] = he_w1[f * HD + lane];
        const float b1 = he_b1[lane];
        #pragma unroll
        for (int rr = 0; rr < 4; ++rr) {
            const int row = wv * 4 + rr, n = n0 + row;
            const float* efb = enemy_feats + (size_t)n * (N_EN * E_FEAT);
            float pf[E_FEAT];
            #pragma unroll
            for (int f = 0; f < E_FEAT; ++f) pf[f] = 0.f;
            #pragma unroll
            for (int e = 0; e < N_EN; ++e) {
                float ef[E_FEAT];
                #pragma unroll
                for (int f = 0; f < E_FEAT; ++f) ef[f] = efb[e * E_FEAT + f];
                float acc = b1;
                #pragma unroll
                for (int f = 0; f < E_FEAT; ++f) acc += ef[f] * w1[f];
                const float r = fmaxf(acc, 0.f);
                #pragma unroll
                for (int f = 0; f < E_FEAT; ++f) pf[f] += r * ef[f];
            }
            ushort* Pr = P + row * P_STRIDE;
            #pragma unroll
            for (int f = 0; f < E_FEAT; ++f) Pr[f * HD + lane] = f2u(pf[f]);
            if (lane < E_FEAT) {            // sef lane-parallel (no per-lane sf[9] array)
                float sv = 0.f;
                #pragma unroll
                for (int e = 0; e < N_EN; ++e) sv += efb[e * E_FEAT + lane];
                Pr[576 + lane] = f2u(sv);
            }
            if (lane == 20) Pr[601] = 0x3F80;
            if (lane < OWN_FEAT) Pr[585 + lane] = f2u(own_feats[(size_t)n * OWN_FEAT + lane]);
            const int ai = agent_idx[n], la = last_act_idx[n];
            if (lane < 8)      Pr[602 + lane] = (lane == ai) ? 0x3F80 : 0;
            if (lane < N_ACT)  Pr[610 + lane] = (lane == la) ? 0x3F80 : 0;
            if (lane < 16)     Pr[624 + lane] = 0;
        }
    }
    __syncthreads();

    // ===== Phase 2: enemy GEMM (bounded unroll, setprio) =====
    f32x4 accE = {0.f, 0.f, 0.f, 0.f};
    __builtin_amdgcn_s_setprio(1);
    #pragma unroll 5
    for (int s = 0; s < KSE; ++s) {
        short8 b = *(const short8*)(ws + BE_OFF + ((size_t)(s * 4 + wv) * 64 + lane) * 8);
        short8 a = lda(smem, arow, P_STRIDE * 2, s, g);
        accE = __builtin_amdgcn_mfma_f32_16x16x32_bf16(a, b, accE, 0, 0, 0);
    }
    __builtin_amdgcn_s_setprio(0);
    __syncthreads();

    // ===== Phase 3: ally P-build; saf lane-parallel =====
    {
        float w1[A_FEAT];
        #pragma unroll
        for (int f = 0; f < A_FEAT; ++f) w1[f] = ha_w1[f * HD + lane];
        const float b1 = ha_b1[lane];
        #pragma unroll
        for (int rr = 0; rr < 4; ++rr) {
            const int row = wv * 4 + rr, n = n0 + row;
            const float* afb = ally_feats + (size_t)n * (N_AL * A_FEAT);
            float pf[A_FEAT];
            #pragma unroll
            for (int f = 0; f < A_FEAT; ++f) pf[f] = 0.f;
            #pragma unroll
            for (int e = 0; e < N_AL; ++e) {
                float af[A_FEAT];
                #pragma unroll
                for (int f = 0; f < A_FEAT; ++f) af[f] = afb[e * A_FEAT + f];
                float acc = b1;
                #pragma unroll
                for (int f = 0; f < A_FEAT; ++f) acc += af[f] * w1[f];
                const float r = fmaxf(acc, 0.f);
                #pragma unroll
                for (int f = 0; f < A_FEAT; ++f) pf[f] += r * af[f];
            }
            ushort* Pr = P + row * P_STRIDE;
            #pragma unroll
            for (int f = 0; f < A_FEAT; ++f) Pr[f * HD + lane] = f2u(pf[f]);
            if (lane < A_FEAT) {            // saf lane-parallel
                float sv = 0.f;
                #pragma unroll
                for (int e = 0; e < N_AL; ++e) sv += afb[e * A_FEAT + lane];
                Pr[640 + lane] = f2u(sv);
            }
            if (lane < 22) Pr[650 + lane] = 0;
        }
    }
    __syncthreads();

    // ===== Phase 4: ally GEMM (bounded unroll, setprio) =====
    __builtin_amdgcn_s_setprio(1);
    #pragma unroll 7
    for (int s = 0; s < KSA; ++s) {
        short8 b = *(const short8*)(ws + BA_OFF + ((size_t)(s * 4 + wv) * 64 + lane) * 8);
        short8 a = lda(smem, arow, P_STRIDE * 2, s, g);
        accE = __builtin_amdgcn_mfma_f32_16x16x32_bf16(a, b, accE, 0, 0, 0);
    }
    __builtin_amdgcn_s_setprio(0);
    __syncthreads();

    // ===== Phase 5: stage A_gru = [x | h | 1 | 0] =====
    #pragma unroll
    for (int j = 0; j < 4; ++j) {
        const int m = g * 4 + j;
        *(ushort*)(smem + LDS_AG + m * 328 + (wv * 16 + arow) * 2) = f2u(fmaxf(accE[j], 0.f));
    }
    {
        const int row = tid >> 4, c4 = (tid & 15) * 4;
        float4 h4 = *(const float4*)(hidden_state + (size_t)(n0 + row) * HD + c4);
        char* p = smem + LDS_AG + row * 328 + (64 + c4) * 2;
        *(uint*)p       = pk2(h4.x, h4.y);
        *(uint*)(p + 4) = pk2(h4.z, h4.w);
        if (tid < 16) *(ushort*)(smem + LDS_AG + tid * 328 + 128 * 2) = 0x3F80;
        for (int i = tid; i < 16 * 31; i += 256) {
            int r2 = i / 31, c = 129 + i % 31;
            *(ushort*)(smem + LDS_AG + r2 * 328 + c * 2) = 0;
        }
    }
    __syncthreads();

    // ===== Phase 6: GRU GEMM (N=256, setprio) =====
    {
        f32x4 accG[4] = {{0.f,0.f,0.f,0.f},{0.f,0.f,0.f,0.f},{0.f,0.f,0.f,0.f},{0.f,0.f,0.f,0.f}};
        __builtin_amdgcn_s_setprio(1);
        #pragma unroll
        for (int s = 0; s < KSG; ++s) {
            short8 a = lda(smem + LDS_AG, arow, 328, s, g);
            #pragma unroll
            for (int tt = 0; tt < 4; ++tt) {
                const int t = wv * 4 + tt;
                short8 b = *(const short8*)(ws + BG_OFF + ((size_t)(s * 16 + t) * 64 + lane) * 8);
                accG[tt] = __builtin_amdgcn_mfma_f32_16x16x32_bf16(a, b, accG[tt], 0, 0, 0);
            }
        }
        __builtin_amdgcn_s_setprio(0);
        #pragma unroll
        for (int tt = 0; tt < 4; ++tt)
            #pragma unroll
            for (int j = 0; j < 4; ++j) {
                const int m = g * 4 + j, jc = (wv * 4 + tt) * 16 + arow;
                *(ushort*)(smem + LDS_GATES + m * 520 + jc * 2) = f2u(accG[tt][j]);
            }
    }
    __syncthreads();

    // ===== Phase 7: pointwise GRU + stage A_u =====
    {
        const int row = tid >> 4, c4 = (tid & 15) * 4;
        const char* gb = smem + LDS_GATES + row * 520;
        uint2 rv = *(const uint2*)(gb + c4 * 2);
        uint2 zv = *(const uint2*)(gb + 128 + c4 * 2);
        uint2 iv = *(const uint2*)(gb + 256 + c4 * 2);
        uint2 nv = *(const uint2*)(gb + 384 + c4 * 2);
        float4 h4 = *(const float4*)(hidden_state + (size_t)(n0 + row) * HD + c4);
        float hr[4] = {u2f(rv.x & 0xffffu), u2f(rv.x >> 16), u2f(rv.y & 0xffffu), u2f(rv.y >> 16)};
        float hz[4] = {u2f(zv.x & 0xffffu), u2f(zv.x >> 16), u2f(zv.y & 0xffffu), u2f(zv.y >> 16)};
        float hi[4] = {u2f(iv.x & 0xffffu), u2f(iv.x >> 16), u2f(iv.y & 0xffffu), u2f(iv.y >> 16)};
        float hn[4] = {u2f(nv.x & 0xffffu), u2f(nv.x >> 16), u2f(nv.y & 0xffffu), u2f(nv.y >> 16)};
        float hcur[4] = {h4.x, h4.y, h4.z, h4.w};
        float hh[4];
        #pragma unroll
        for (int cc = 0; cc < 4; ++cc) {
            const float r = sigm(hr[cc]);
            const float z = sigm(hz[cc]);
            const float nng = tanhf(hi[cc] + r * hn[cc]);
            hh[cc] = (1.f - z) * nng + z * hcur[cc];
        }
        *(float4*)(out_hh + (size_t)(n0 + row) * HD + c4) = make_float4(hh[0], hh[1], hh[2], hh[3]);
        char* p = smem + LDS_AU + row * 200 + c4 * 2;
        *(uint*)p       = pk2(hh[0], hh[1]);
        *(uint*)(p + 4) = pk2(hh[2], hh[3]);
        if (tid < 16) *(ushort*)(smem + LDS_AU + tid * 200 + 64 * 2) = 0x3F80;
        for (int i = tid; i < 16 * 31; i += 256) {
            int r2 = i / 31, c = 65 + i % 31;
            *(ushort*)(smem + LDS_AU + r2 * 200 + c * 2) = 0;
        }
    }
    __syncthreads();

    // ===== Phase 8: u-GEMM (N=80, setprio) =====
    {
        f32x4 accU = {0.f, 0.f, 0.f, 0.f};
        f32x4 accQ = {0.f, 0.f, 0.f, 0.f};
        __builtin_amdgcn_s_setprio(1);
        #pragma unroll
        for (int s = 0; s < KSU; ++s) {
            short8 a = lda(smem + LDS_AU, arow, 200, s, g);
            short8 b = *(const short8*)(ws + BU_OFF + ((size_t)(s * 5 + wv) * 64 + lane) * 8);
            accU = __builtin_amdgcn_mfma_f32_16x16x32_bf16(a, b, accU, 0, 0, 0);
            if (wv == 0) {
                short8 b2 = *(const short8*)(ws + BU_OFF + ((size_t)(s * 5 + 4) * 64 + lane) * 8);
                accQ = __builtin_amdgcn_mfma_f32_16x16x32_bf16(a, b2, accQ, 0, 0, 0);
            }
        }
        __builtin_amdgcn_s_setprio(0);
        float* uld = (float*)(smem + LDS_U);
        #pragma unroll
        for (int j = 0; j < 4; ++j) {
            const int m = g * 4 + j;
            uld[m * 66 + wv * 16 + arow] = accU[j];
        }
        if (wv == 0) {
            #pragma unroll
            for (int j = 0; j < 4; ++j) {
                const int m = g * 4 + j;
                if (arow < 6)       out_q[(size_t)(n0 + m) * N_ACT + arow] = accQ[j];
                else if (arow == 6) uld[m * 66 + 64] = accQ[j];
            }
        }
    }
    __syncthreads();

    // ===== Phase 9: attack head (r recomputed; wave wv owns rows 4wv..4wv+3) =====
    {
        float w1[E_FEAT];
        #pragma unroll
        for (int f = 0; f < E_FEAT; ++f) w1[f] = he_w1[f * HD + lane];
        const float b1 = he_b1[lane];
        const float* uld = (const float*)(smem + LDS_U);
        #pragma unroll
        for (int rr = 0; rr < 4; ++rr) {
            const int row = wv * 4 + rr, n = n0 + row;
            const float uk = uld[row * 66 + lane];
            const float ct = uld[row * 66 + 64];
            const float* efb = enemy_feats + (size_t)n * (N_EN * E_FEAT);
            float p[N_EN];
            #pragma unroll
            for (int e = 0; e < N_EN; ++e) {
                float acc = b1;
                #pragma unroll
                for (int f = 0; f < E_FEAT; ++f) acc += efb[e * E_FEAT + f] * w1[f];
                p[e] = fmaxf(acc, 0.f) * uk;
            }
            #pragma unroll
            for (int o = 1; o < 64; o <<= 1) {
                #pragma unroll
                for (int e = 0; e < N_EN; ++e) p[e] += __shfl_xor(p[e], o);
            }
            if (lane < N_EN) {
                float pv = p[0];
                #pragma unroll
                for (int e = 1; e < N_EN; ++e) if (lane == e) pv = p[e];
                out_q[(size_t)n * N_ACT + 6 + lane] = pv + ct;
            }
        }
    }
}

extern "C" void kernel_launch(void* const* d_in, const int* in_sizes, int n_in,
                              void* d_out, int out_size, void* d_ws, size_t ws_size,
                              hipStream_t stream) {
    const float* own_feats    = (const float*)d_in[0];
    const float* enemy_feats  = (const float*)d_in[1];
    const float* ally_feats   = (const float*)d_in[2];
    const float* hidden_state = (const float*)d_in[3];
    const int*  agent_idx     = (const int*)d_in[4];
    const int*  last_act      = (const int*)d_in[5];
    const float* fc1_own_w = (const float*)d_in[7];
    const float* fc1_own_b = (const float*)d_in[8];
    const float* agent_id_emb  = (const float*)d_in[9];
    const float* action_id_emb = (const float*)d_in[10];
    const float* he_w1 = (const float*)d_in[11];
    const float* he_b1 = (const float*)d_in[12];
    const float* he_w2 = (const float*)d_in[13];
    const float* he_b2 = (const float*)d_in[14];
    const float* ha_w1 = (const float*)d_in[15];
    const float* ha_b1 = (const float*)d_in[16];
    const float* ha_w2 = (const float*)d_in[17];
    const float* ha_b2 = (const float*)d_in[18];
    const float* gru_w_ih = (const float*)d_in[19];
    const float* gru_w_hh = (const float*)d_in[20];
    const float* gru_b_ih = (const float*)d_in[21];
    const float* gru_b_hh = (const float*)d_in[22];
    const float* fc2_w = (const float*)d_in[23];
    const float* fc2_b = (const float*)d_in[24];

    const int R = in_sizes[0] / OWN_FEAT;  // 32768
    ushort* ws = (ushort*)d_ws;
    float* out_q  = (float*)d_out;
    float* out_hh = out_q + (size_t)R * N_ACT;

    prep_kernel<<<65, 256, 0, stream>>>(
        he_w2, he_b2, ha_w2, ha_b2, fc1_own_w, fc1_own_b,
        agent_id_emb, action_id_emb, gru_w_ih, gru_w_hh, gru_b_ih, gru_b_hh,
        fc2_w, fc2_b, ws);

    agent_kernel<<<R / 16, 256, 0, stream>>>(
        own_feats, enemy_feats, ally_feats, hidden_state, agent_idx, last_act,
        he_w1, he_b1, ha_w1, ha_b1, ws, out_q, out_hh);
}

// Round 18
// 90.604 us; speedup vs baseline: 1.8765x; 1.0109x over previous
//
#include <hip/hip_runtime.h>
#include <hip/hip_bf16.h>

typedef short short8 __attribute__((ext_vector_type(8)));
typedef float f32x4 __attribute__((ext_vector_type(4)));

#define HD 64
#define N_EN 8
#define N_AL 7
#define E_FEAT 9
#define A_FEAT 10
#define OWN_FEAT 16
#define N_ACT 14
#define EW2 641
#define AW2 640

// P buffer: [16][640] ushort, XOR-swizzled by ((row&7)<<3) in ushort units (16-B granules)
#define PW 640
#define LDS_BYTES 20480   // == 160KiB / 8 blocks exactly
// back-half regions (P dead after phase 4)
#define AG_OFF 0          // [16] rows x 132 us, stride 264 B (K=128: x|h)
#define AG_STR 264
#define GATES_OFF 4352    // [16] x 260 us, stride 520 B (N=256)
#define GT_STR 520
#define AU_OFF 12672      // [16] x 68 us, stride 136 B (K=64: hh)
#define AU_STR 136
#define U_OFF 0           // [16][66] f32 (4224 B), overlaps dead AG

// B tables in ws (ushort units)
#define BE_OFF 0          // enemy K=640: 20 s x 4 t
#define BA_OFF 40960      // ally  K=640: 20 s x 4 t
#define BG_OFF 81920      // gru   K=128, N=256: 4 s x 16 t
#define BU_OFF 114688     // u     K=64,  N=80:  2 s x 5 t
#define WS_US 119808
// fbias (float*)(ws+WS_US): [0..127] r|z comb bias, [128..191] b_in, [192..255] b_hn,
//                           [256..319] ub, [320..325] qb, [326] cb

__device__ __forceinline__ ushort f2u(float x) {
    __hip_bfloat16 b = __float2bfloat16(x);
    ushort u; __builtin_memcpy(&u, &b, 2); return u;
}
__device__ __forceinline__ float u2f(uint u) {
    union { uint x; float f; } c; c.x = u << 16; return c.f;
}
__device__ __forceinline__ uint pk2(float a, float b) {
    return (uint)f2u(a) | ((uint)f2u(b) << 16);
}
__device__ __forceinline__ float sigm(float x) { return 1.f / (1.f + __expf(-x)); }

__device__ __forceinline__ short8 lda_swz(const ushort* P_us, int row, int s, int g) {
    const int mm = (row & 7) << 3;
    const int o = s * 32 + g * 4;
    const ushort* pr = P_us + row * PW;
    union { short8 v; uint2 q[2]; } u;
    u.q[0] = *(const uint2*)(pr + (o ^ mm));
    u.q[1] = *(const uint2*)(pr + ((o + 16) ^ mm));
    return u.v;
}
__device__ __forceinline__ short8 lda_lin(const char* base, int row, int strideB, int s, int g) {
    const char* p = base + row * strideB + s * 64 + g * 8;
    union { short8 v; uint2 q[2]; } u;
    u.q[0] = *(const uint2*)p;
    u.q[1] = *(const uint2*)(p + 32);
    return u.v;
}

// ---------------- prep: B tables + fbias ----------------
__global__ __launch_bounds__(256) void prep_kernel(
    const float* __restrict__ he_w2, const float* __restrict__ he_b2,
    const float* __restrict__ ha_w2, const float* __restrict__ ha_b2,
    const float* __restrict__ fc1_own_w, const float* __restrict__ fc1_own_b,
    const float* __restrict__ agent_id_emb, const float* __restrict__ action_id_emb,
    const float* __restrict__ gru_w_ih, const float* __restrict__ gru_w_hh,
    const float* __restrict__ gru_b_ih, const float* __restrict__ gru_b_hh,
    const float* __restrict__ fc2_w, const float* __restrict__ fc2_b,
    ushort* __restrict__ ws, float* __restrict__ fbias)
{
    const int GE = 80, GA = 80, GG = 64, GU = 10;
    const int TT = (GE + GA + GG + GU) * 64;   // 14976
    int idx = blockIdx.x * 256 + threadIdx.x;
    if (idx < TT) {
        int grp = idx >> 6, lane = idx & 63;
        int g = lane >> 4, col16 = lane & 15;
        int table, s, t, slot;
        if (grp < GE)                { table = 0; int q = grp;                s = q / 4;  t = q % 4;  slot = q * 64 + lane; }
        else if (grp < GE + GA)      { table = 1; int q = grp - GE;           s = q / 4;  t = q % 4;  slot = q * 64 + lane; }
        else if (grp < GE + GA + GG) { table = 2; int q = grp - GE - GA;      s = q / 16; t = q % 16; slot = q * 64 + lane; }
        else                         { table = 3; int q = grp - GE - GA - GG; s = q / 5;  t = q % 5;  slot = q * 64 + lane; }
        const int j = t * 16 + col16;
        ushort out[8];
        #pragma unroll
        for (int e = 0; e < 8; ++e) {
            int kk = 32 * s + 4 * g + (e & 3) + 16 * (e >> 2);
            float v = 0.f;
            if (table == 0) {
                if (kk < 576)       v = he_w2[(kk & 63) * EW2 + (kk >> 6) * HD + j];
                else if (kk < 585)  v = he_b2[(kk - 576) * HD + j];
                else if (kk < 601)  v = fc1_own_w[(kk - 585) * HD + j];
                else if (kk == 601) v = fc1_own_b[j];
                else if (kk < 610)  v = agent_id_emb[(kk - 602) * HD + j];
                else if (kk < 624)  v = action_id_emb[(kk - 610) * HD + j];
                else if (kk < 634)  v = ha_b2[(kk - 624) * HD + j];
            } else if (table == 1) {
                v = ha_w2[(kk & 63) * AW2 + (kk >> 6) * HD + j];
            } else if (table == 2) {
                int gb2 = j >> 6, c = j & 63;
                int jj = (gb2 == 0) ? c : (gb2 == 1) ? 64 + c : 128 + c;
                if (gb2 <= 1)      v = (kk < 64) ? gru_w_ih[jj * HD + kk] : gru_w_hh[jj * HD + kk - 64];
                else if (gb2 == 2) v = (kk < 64) ? gru_w_ih[jj * HD + kk] : 0.f;
                else               v = (kk >= 64) ? gru_w_hh[jj * HD + kk - 64] : 0.f;
            } else {
                if (kk < 64) {
                    if (j < 64)       v = he_w2[j * EW2 + 576 + kk];
                    else if (j < 70)  v = fc2_w[kk * 6 + (j - 64)];
                    else if (j == 70) v = he_b2[576 + kk];
                }
            }
            out[e] = f2u(v);
        }
        ushort* dst = ws + ((table == 0) ? BE_OFF : (table == 1) ? BA_OFF : (table == 2) ? BG_OFF : BU_OFF);
        *(short8*)(dst + (size_t)slot * 8) = *(short8*)out;
    } else {
        int b = idx - TT;
        if (b < 128)       fbias[b] = gru_b_ih[b] + gru_b_hh[b];
        else if (b < 192)  fbias[b] = gru_b_ih[b];
        else if (b < 256)  fbias[b] = gru_b_hh[b - 64];
        else if (b < 320)  fbias[b] = he_w2[(size_t)(b - 256) * EW2 + 640];
        else if (b < 326)  fbias[b] = fc2_b[b - 320];
        else if (b == 326) fbias[326] = he_b2[640];
    }
}

// ---------------- main: 4 waves / 16 rows, 20480B LDS (8 blocks/CU), 64 VGPR ----------------
__global__ __launch_bounds__(256, 4) void agent_kernel(
    const float* __restrict__ own_feats,
    const float* __restrict__ enemy_feats,
    const float* __restrict__ ally_feats,
    const float* __restrict__ hidden_state,
    const int*  __restrict__ agent_idx,
    const int*  __restrict__ last_act_idx,
    const float* __restrict__ he_w1, const float* __restrict__ he_b1,
    const float* __restrict__ ha_w1, const float* __restrict__ ha_b1,
    const ushort* __restrict__ ws, const float* __restrict__ fbias,
    float* __restrict__ out_q, float* __restrict__ out_hh)
{
    __shared__ __align__(16) char smem[LDS_BYTES];
    const int tid  = threadIdx.x;
    const int lane = tid & 63;
    const int wv   = tid >> 6;
    const int n0   = blockIdx.x * 16;
    const int arow = lane & 15;
    const int g    = lane >> 4;
    ushort* P = (ushort*)smem;

    // ===== Phase 1: enemy P-build (rows 4wv..4wv+3), swizzled; sef/saf lane-parallel =====
    {
        float w1[E_FEAT];
        #pragma unroll
        for (int f = 0; f < E_FEAT; ++f) w1[f] = he_w1[f * HD + lane];
        const float b1 = he_b1[lane];
        #pragma unroll
        for (int rr = 0; rr < 4; ++rr) {
            const int row = wv * 4 + rr, n = n0 + row;
            const int mm = (row & 7) << 3;
            const float* efb = enemy_feats + (size_t)n * (N_EN * E_FEAT);
            float pf[E_FEAT];
            #pragma unroll
            for (int f = 0; f < E_FEAT; ++f) pf[f] = 0.f;
            #pragma unroll
            for (int e = 0; e < N_EN; ++e) {
                float ef[E_FEAT];
                #pragma unroll
                for (int f = 0; f < E_FEAT; ++f) ef[f] = efb[e * E_FEAT + f];
                float acc = b1;
                #pragma unroll
                for (int f = 0; f < E_FEAT; ++f) acc += ef[f] * w1[f];
                const float r = fmaxf(acc, 0.f);
                #pragma unroll
                for (int f = 0; f < E_FEAT; ++f) pf[f] += r * ef[f];
            }
            ushort* Pr = P + row * PW;
            #pragma unroll
            for (int f = 0; f < E_FEAT; ++f) Pr[(f * HD + lane) ^ mm] = f2u(pf[f]);
            if (lane < E_FEAT) {
                float sv = 0.f;
                #pragma unroll
                for (int e = 0; e < N_EN; ++e) sv += efb[e * E_FEAT + lane];
                Pr[(576 + lane) ^ mm] = f2u(sv);
            }
            if (lane < OWN_FEAT) Pr[(585 + lane) ^ mm] = f2u(own_feats[(size_t)n * OWN_FEAT + lane]);
            if (lane == 20) Pr[601 ^ mm] = 0x3F80;
            const int ai = agent_idx[n], la = last_act_idx[n];
            if (lane < 8)      Pr[(602 + lane) ^ mm] = (lane == ai) ? (ushort)0x3F80 : (ushort)0;
            if (lane < N_ACT)  Pr[(610 + lane) ^ mm] = (lane == la) ? (ushort)0x3F80 : (ushort)0;
            if (lane < A_FEAT) {
                const float* afb = ally_feats + (size_t)n * (N_AL * A_FEAT);
                float sv = 0.f;
                #pragma unroll
                for (int e = 0; e < N_AL; ++e) sv += afb[e * A_FEAT + lane];
                Pr[(624 + lane) ^ mm] = f2u(sv);
            }
            if (lane < 6) Pr[(634 + lane) ^ mm] = 0;
        }
    }
    __syncthreads();

    // ===== Phase 2: enemy GEMM K=640 (bounded unroll, setprio) =====
    f32x4 accE = {0.f, 0.f, 0.f, 0.f};
    __builtin_amdgcn_s_setprio(1);
    #pragma unroll 5
    for (int s = 0; s < 20; ++s) {
        short8 b = *(const short8*)(ws + BE_OFF + ((size_t)(s * 4 + wv) * 64 + lane) * 8);
        short8 a = lda_swz(P, arow, s, g);
        accE = __builtin_amdgcn_mfma_f32_16x16x32_bf16(a, b, accE, 0, 0, 0);
    }
    __builtin_amdgcn_s_setprio(0);
    __syncthreads();

    // ===== Phase 3: ally P-build (overwrites all 640 cols), swizzled =====
    {
        float w1[A_FEAT];
        #pragma unroll
        for (int f = 0; f < A_FEAT; ++f) w1[f] = ha_w1[f * HD + lane];
        const float b1 = ha_b1[lane];
        #pragma unroll
        for (int rr = 0; rr < 4; ++rr) {
            const int row = wv * 4 + rr, n = n0 + row;
            const int mm = (row & 7) << 3;
            const float* afb = ally_feats + (size_t)n * (N_AL * A_FEAT);
            float pf[A_FEAT];
            #pragma unroll
            for (int f = 0; f < A_FEAT; ++f) pf[f] = 0.f;
            #pragma unroll
            for (int e = 0; e < N_AL; ++e) {
                float af[A_FEAT];
                #pragma unroll
                for (int f = 0; f < A_FEAT; ++f) af[f] = afb[e * A_FEAT + f];
                float acc = b1;
                #pragma unroll
                for (int f = 0; f < A_FEAT; ++f) acc += af[f] * w1[f];
                const float r = fmaxf(acc, 0.f);
                #pragma unroll
                for (int f = 0; f < A_FEAT; ++f) pf[f] += r * af[f];
            }
            ushort* Pr = P + row * PW;
            #pragma unroll
            for (int f = 0; f < A_FEAT; ++f) Pr[(f * HD + lane) ^ mm] = f2u(pf[f]);
        }
    }
    __syncthreads();

    // ===== Phase 4: ally GEMM K=640 (bounded unroll, setprio) =====
    __builtin_amdgcn_s_setprio(1);
    #pragma unroll 5
    for (int s = 0; s < 20; ++s) {
        short8 b = *(const short8*)(ws + BA_OFF + ((size_t)(s * 4 + wv) * 64 + lane) * 8);
        short8 a = lda_swz(P, arow, s, g);
        accE = __builtin_amdgcn_mfma_f32_16x16x32_bf16(a, b, accE, 0, 0, 0);
    }
    __builtin_amdgcn_s_setprio(0);
    __syncthreads();

    // ===== Phase 5: stage A_gru = [x | h] (K=128, no const/pad) =====
    #pragma unroll
    for (int j = 0; j < 4; ++j) {
        const int m = g * 4 + j;
        *(ushort*)(smem + AG_OFF + m * AG_STR + (wv * 16 + arow) * 2) = f2u(fmaxf(accE[j], 0.f));
    }
    {
        const int row = tid >> 4, c4 = (tid & 15) * 4;
        float4 h4 = *(const float4*)(hidden_state + (size_t)(n0 + row) * HD + c4);
        char* p = smem + AG_OFF + row * AG_STR + (64 + c4) * 2;
        *(uint*)p       = pk2(h4.x, h4.y);
        *(uint*)(p + 4) = pk2(h4.z, h4.w);
    }
    __syncthreads();

    // ===== Phase 6: GRU GEMM K=128, N=256 (setprio); bias folded at write =====
    {
        f32x4 accG[4] = {{0.f,0.f,0.f,0.f},{0.f,0.f,0.f,0.f},{0.f,0.f,0.f,0.f},{0.f,0.f,0.f,0.f}};
        __builtin_amdgcn_s_setprio(1);
        #pragma unroll
        for (int s = 0; s < 4; ++s) {
            short8 a = lda_lin(smem + AG_OFF, arow, AG_STR, s, g);
            #pragma unroll
            for (int tt = 0; tt < 4; ++tt) {
                const int t = wv * 4 + tt;
                short8 b = *(const short8*)(ws + BG_OFF + ((size_t)(s * 16 + t) * 64 + lane) * 8);
                accG[tt] = __builtin_amdgcn_mfma_f32_16x16x32_bf16(a, b, accG[tt], 0, 0, 0);
            }
        }
        __builtin_amdgcn_s_setprio(0);
        #pragma unroll
        for (int tt = 0; tt < 4; ++tt) {
            const int jc = (wv * 4 + tt) * 16 + arow;
            const float bt = fbias[jc];
            #pragma unroll
            for (int j = 0; j < 4; ++j) {
                const int m = g * 4 + j;
                *(ushort*)(smem + GATES_OFF + m * GT_STR + jc * 2) = f2u(accG[tt][j] + bt);
            }
        }
    }
    __syncthreads();

    // ===== Phase 7: pointwise GRU + stage A_u (biases already in gates) =====
    {
        const int row = tid >> 4, c4 = (tid & 15) * 4;
        const char* gb = smem + GATES_OFF + row * GT_STR;
        uint2 rv = *(const uint2*)(gb + c4 * 2);
        uint2 zv = *(const uint2*)(gb + 128 + c4 * 2);
        uint2 iv = *(const uint2*)(gb + 256 + c4 * 2);
        uint2 nv = *(const uint2*)(gb + 384 + c4 * 2);
        float4 h4 = *(const float4*)(hidden_state + (size_t)(n0 + row) * HD + c4);
        float hr[4] = {u2f(rv.x & 0xffffu), u2f(rv.x >> 16), u2f(rv.y & 0xffffu), u2f(rv.y >> 16)};
        float hz[4] = {u2f(zv.x & 0xffffu), u2f(zv.x >> 16), u2f(zv.y & 0xffffu), u2f(zv.y >> 16)};
        float hi[4] = {u2f(iv.x & 0xffffu), u2f(iv.x >> 16), u2f(iv.y & 0xffffu), u2f(iv.y >> 16)};
        float hn[4] = {u2f(nv.x & 0xffffu), u2f(nv.x >> 16), u2f(nv.y & 0xffffu), u2f(nv.y >> 16)};
        float hcur[4] = {h4.x, h4.y, h4.z, h4.w};
        float hh[4];
        #pragma unroll
        for (int cc = 0; cc < 4; ++cc) {
            const float r = sigm(hr[cc]);
            const float z = sigm(hz[cc]);
            const float nng = tanhf(hi[cc] + r * hn[cc]);
            hh[cc] = (1.f - z) * nng + z * hcur[cc];
        }
        *(float4*)(out_hh + (size_t)(n0 + row) * HD + c4) = make_float4(hh[0], hh[1], hh[2], hh[3]);
        char* p = smem + AU_OFF + row * AU_STR + c4 * 2;
        *(uint*)p       = pk2(hh[0], hh[1]);
        *(uint*)(p + 4) = pk2(hh[2], hh[3]);
    }
    __syncthreads();

    // ===== Phase 8: u-GEMM K=64, N=80 (setprio); ub/qb/cb folded at write =====
    {
        f32x4 accU = {0.f, 0.f, 0.f, 0.f};
        f32x4 accQ = {0.f, 0.f, 0.f, 0.f};
        __builtin_amdgcn_s_setprio(1);
        #pragma unroll
        for (int s = 0; s < 2; ++s) {
            short8 a = lda_lin(smem + AU_OFF, arow, AU_STR, s, g);
            short8 b = *(const short8*)(ws + BU_OFF + ((size_t)(s * 5 + wv) * 64 + lane) * 8);
            accU = __builtin_amdgcn_mfma_f32_16x16x32_bf16(a, b, accU, 0, 0, 0);
            if (wv == 0) {
                short8 b2 = *(const short8*)(ws + BU_OFF + ((size_t)(s * 5 + 4) * 64 + lane) * 8);
                accQ = __builtin_amdgcn_mfma_f32_16x16x32_bf16(a, b2, accQ, 0, 0, 0);
            }
        }
        __builtin_amdgcn_s_setprio(0);
        float* uld = (float*)(smem + U_OFF);
        const float ub = fbias[256 + wv * 16 + arow];
        #pragma unroll
        for (int j = 0; j < 4; ++j) {
            const int m = g * 4 + j;
            uld[m * 66 + wv * 16 + arow] = accU[j] + ub;
        }
        if (wv == 0) {
            #pragma unroll
            for (int j = 0; j < 4; ++j) {
                const int m = g * 4 + j;
                if (arow < 6)       out_q[(size_t)(n0 + m) * N_ACT + arow] = accQ[j] + fbias[320 + arow];
                else if (arow == 6) uld[m * 66 + 64] = accQ[j] + fbias[326];
            }
        }
    }
    __syncthreads();

    // ===== Phase 9: attack head (r recomputed; u/c already biased) =====
    {
        float w1[E_FEAT];
        #pragma unroll
        for (int f = 0; f < E_FEAT; ++f) w1[f] = he_w1[f * HD + lane];
        const float b1 = he_b1[lane];
        const float* uld = (const float*)(smem + U_OFF);
        #pragma unroll
        for (int rr = 0; rr < 4; ++rr) {
            const int row = wv * 4 + rr, n = n0 + row;
            const float uk = uld[row * 66 + lane];
            const float ct = uld[row * 66 + 64];
            const float* efb = enemy_feats + (size_t)n * (N_EN * E_FEAT);
            float p[N_EN];
            #pragma unroll
            for (int e = 0; e < N_EN; ++e) {
                float acc = b1;
                #pragma unroll
                for (int f = 0; f < E_FEAT; ++f) acc += efb[e * E_FEAT + f] * w1[f];
                p[e] = fmaxf(acc, 0.f) * uk;
            }
            #pragma unroll
            for (int o = 1; o < 64; o <<= 1) {
                #pragma unroll
                for (int e = 0; e < N_EN; ++e) p[e] += __shfl_xor(p[e], o);
            }
            if (lane < N_EN) {
                float pv = p[0];
                #pragma unroll
                for (int e = 1; e < N_EN; ++e) if (lane == e) pv = p[e];
                out_q[(size_t)n * N_ACT + 6 + lane] = pv + ct;
            }
        }
    }
}

extern "C" void kernel_launch(void* const* d_in, const int* in_sizes, int n_in,
                              void* d_out, int out_size, void* d_ws, size_t ws_size,
                              hipStream_t stream) {
    const float* own_feats    = (const float*)d_in[0];
    const float* enemy_feats  = (const float*)d_in[1];
    const float* ally_feats   = (const float*)d_in[2];
    const float* hidden_state = (const float*)d_in[3];
    const int*  agent_idx     = (const int*)d_in[4];
    const int*  last_act      = (const int*)d_in[5];
    const float* fc1_own_w = (const float*)d_in[7];
    const float* fc1_own_b = (const float*)d_in[8];
    const float* agent_id_emb  = (const float*)d_in[9];
    const float* action_id_emb = (const float*)d_in[10];
    const float* he_w1 = (const float*)d_in[11];
    const float* he_b1 = (const float*)d_in[12];
    const float* he_w2 = (const float*)d_in[13];
    const float* he_b2 = (const float*)d_in[14];
    const float* ha_w1 = (const float*)d_in[15];
    const float* ha_b1 = (const float*)d_in[16];
    const float* ha_w2 = (const float*)d_in[17];
    const float* ha_b2 = (const float*)d_in[18];
    const float* gru_w_ih = (const float*)d_in[19];
    const float* gru_w_hh = (const float*)d_in[20];
    const float* gru_b_ih = (const float*)d_in[21];
    const float* gru_b_hh = (const float*)d_in[22];
    const float* fc2_w = (const float*)d_in[23];
    const float* fc2_b = (const float*)d_in[24];

    const int R = in_sizes[0] / OWN_FEAT;  // 32768
    ushort* ws = (ushort*)d_ws;
    float* fbias = (float*)(ws + WS_US);
    float* out_q  = (float*)d_out;
    float* out_hh = out_q + (size_t)R * N_ACT;

    prep_kernel<<<60, 256, 0, stream>>>(
        he_w2, he_b2, ha_w2, ha_b2, fc1_own_w, fc1_own_b,
        agent_id_emb, action_id_emb, gru_w_ih, gru_w_hh, gru_b_ih, gru_b_hh,
        fc2_w, fc2_b, ws, fbias);

    agent_kernel<<<R / 16, 256, 0, stream>>>(
        own_feats, enemy_feats, ally_feats, hidden_state, agent_idx, last_act,
        he_w1, he_b1, ha_w1, ha_b1, ws, fbias, out_q, out_hh);
}